// Round 1
// baseline (372.768 us; speedup 1.0000x reference)
//
#include <hip/hip_runtime.h>
#include <hip/hip_bf16.h>
#include <math.h>

// ---------------------------------------------------------------------------
// GCN 2-layer forward, fp32. Pipeline:
//   1) zero counters
//   2) histogram of dst (in-degree, excluding self-loop)
//   3) single-block exclusive scan -> row_start; dinv = rsqrt(deg+1)
//   4) counting-sort fill: CSR (sorted_src, sorted_norm) grouped by dst
//      (self-loops appended, norm = dinv[v]^2)
//   5) GEMM1: h1 = x @ W1            (50000x256 @ 256x128, fp32 vector ALU)
//   6) AGG1:  h  = relu(gather-sum(h1[src]*norm) + b1)   [CSR gather, float4]
//   7) GEMM2: h2 = h @ W2            (50000x128 @ 128x16)
//   8) AGG2 + bias + log_softmax fused (16-lane shuffle reductions)
// ---------------------------------------------------------------------------

#define FIN 256
#define FH  128
#define FO  16

__global__ __launch_bounds__(256) void GCN_zero_k(int* __restrict__ count,
                                                  int* __restrict__ cursor, int N) {
    int i = blockIdx.x * 256 + threadIdx.x;
    if (i < N) { count[i] = 0; cursor[i] = 0; }
}

__global__ __launch_bounds__(256) void GCN_hist_k(const int* __restrict__ edge,
                                                  int* __restrict__ count, int E) {
    int i = blockIdx.x * 256 + threadIdx.x;
    if (i < E) atomicAdd(&count[edge[E + i]], 1);
}

// single block, 1024 threads: exclusive scan of (count[v]+1) -> row_start,
// dinv[v] = rsqrt(count[v]+1). row_start[N] = total = E + N.
__global__ __launch_bounds__(1024) void GCN_scan_k(const int* __restrict__ count,
                                                   int* __restrict__ row_start,
                                                   float* __restrict__ dinv, int N) {
    __shared__ int sums[1024];
    int tid = threadIdx.x;
    int chunk = (N + 1023) >> 10;
    int beg = tid * chunk;
    int end = beg + chunk; if (end > N) end = N;
    int s = 0;
    for (int v = beg; v < end && v < N; v++) s += count[v] + 1;
    sums[tid] = s;
    __syncthreads();
    // Hillis-Steele inclusive scan
    for (int off = 1; off < 1024; off <<= 1) {
        int t = (tid >= off) ? sums[tid - off] : 0;
        __syncthreads();
        sums[tid] += t;
        __syncthreads();
    }
    int run = (tid == 0) ? 0 : sums[tid - 1];
    for (int v = beg; v < end && v < N; v++) {
        row_start[v] = run;
        int c = count[v] + 1;
        dinv[v] = rsqrtf((float)c);
        run += c;
    }
    if (end == N) row_start[N] = run;  // idempotent: all tail threads write total
}

__global__ __launch_bounds__(256) void GCN_fill_k(const int* __restrict__ edge,
                                                  const int* __restrict__ row_start,
                                                  int* __restrict__ cursor,
                                                  const float* __restrict__ dinv,
                                                  int* __restrict__ ssrc,
                                                  float* __restrict__ snorm,
                                                  int E, int N) {
    int i = blockIdx.x * 256 + threadIdx.x;
    if (i < E) {
        int s = edge[i];
        int d = edge[E + i];
        int p = atomicAdd(&cursor[d], 1);
        int idx = row_start[d] + p;
        ssrc[idx] = s;
        snorm[idx] = dinv[s] * dinv[d];
    } else if (i < E + N) {
        int v = i - E;
        int p = atomicAdd(&cursor[v], 1);
        int idx = row_start[v] + p;
        ssrc[idx] = v;
        float q = dinv[v];
        snorm[idx] = q * q;
    }
}

// GEMM1: h1[N][128] = x[N][256] @ W1[256][128]. Block: 256 thr, 32 rows.
// 4x4 register tile per thread. K staged in 64-chunks.
#define G1_BR 32
#define G1_KC 64
__global__ __launch_bounds__(256) void GCN_gemm1_k(const float* __restrict__ x,
                                                   const float* __restrict__ W1,
                                                   float* __restrict__ h1, int N) {
    __shared__ __align__(16) float wsh[G1_KC][FH];       // 32 KiB
    __shared__ __align__(16) float xs[G1_BR][G1_KC + 1]; // pad 65 -> bank-spread
    int tid = threadIdx.x;
    int row0 = blockIdx.x * G1_BR;
    int tc = tid & 31;   // col quad: cols 4*tc..4*tc+3
    int tr = tid >> 5;   // row quad: rows 4*tr..4*tr+3
    float acc00 = 0, acc01 = 0, acc02 = 0, acc03 = 0;
    float acc10 = 0, acc11 = 0, acc12 = 0, acc13 = 0;
    float acc20 = 0, acc21 = 0, acc22 = 0, acc23 = 0;
    float acc30 = 0, acc31 = 0, acc32 = 0, acc33 = 0;

    for (int kc = 0; kc < FIN; kc += G1_KC) {
        // load W chunk [64][128]: 8192 floats / 256 thr = 32 each, coalesced
        #pragma unroll
        for (int j = 0; j < (G1_KC * FH) / 256; j++) {
            int i = tid + j * 256;
            wsh[i >> 7][i & 127] = W1[(kc + (i >> 7)) * FH + (i & 127)];
        }
        // load x tile [32][64]: 2048 floats / 256 thr = 8 each, coalesced
        #pragma unroll
        for (int j = 0; j < (G1_BR * G1_KC) / 256; j++) {
            int i = tid + j * 256;
            int r = i >> 6, k = i & 63;
            int gr = row0 + r;
            xs[r][k] = (gr < N) ? x[gr * FIN + kc + k] : 0.f;
        }
        __syncthreads();
        for (int k = 0; k < G1_KC; k++) {
            float4 wv = *(const float4*)&wsh[k][tc * 4];
            float x0 = xs[tr * 4 + 0][k];
            float x1 = xs[tr * 4 + 1][k];
            float x2 = xs[tr * 4 + 2][k];
            float x3 = xs[tr * 4 + 3][k];
            acc00 += x0 * wv.x; acc01 += x0 * wv.y; acc02 += x0 * wv.z; acc03 += x0 * wv.w;
            acc10 += x1 * wv.x; acc11 += x1 * wv.y; acc12 += x1 * wv.z; acc13 += x1 * wv.w;
            acc20 += x2 * wv.x; acc21 += x2 * wv.y; acc22 += x2 * wv.z; acc23 += x2 * wv.w;
            acc30 += x3 * wv.x; acc31 += x3 * wv.y; acc32 += x3 * wv.z; acc33 += x3 * wv.w;
        }
        __syncthreads();
    }
    int gr0 = row0 + tr * 4;
    if (gr0 + 0 < N) { float4 o = {acc00, acc01, acc02, acc03}; *(float4*)&h1[(gr0 + 0) * FH + tc * 4] = o; }
    if (gr0 + 1 < N) { float4 o = {acc10, acc11, acc12, acc13}; *(float4*)&h1[(gr0 + 1) * FH + tc * 4] = o; }
    if (gr0 + 2 < N) { float4 o = {acc20, acc21, acc22, acc23}; *(float4*)&h1[(gr0 + 2) * FH + tc * 4] = o; }
    if (gr0 + 3 < N) { float4 o = {acc30, acc31, acc32, acc33}; *(float4*)&h1[(gr0 + 3) * FH + tc * 4] = o; }
}

// AGG1: h[node][f] = relu(b1[f] + sum_{e in row(node)} h1[src_e][f]*norm_e)
// thread = (node, float4-slot j). 32 threads (=half wave) per node, coalesced
// 512B gather per edge per node.
__global__ __launch_bounds__(256) void GCN_agg1_k(const float* __restrict__ h1,
                                                  const int* __restrict__ row_start,
                                                  const int* __restrict__ ssrc,
                                                  const float* __restrict__ snorm,
                                                  const float* __restrict__ b1,
                                                  float* __restrict__ h, int N) {
    int gid = blockIdx.x * 256 + threadIdx.x;
    int node = gid >> 5;
    if (node >= N) return;
    int j = gid & 31;
    int beg = row_start[node], end = row_start[node + 1];
    const float4* hp = (const float4*)h1;
    float4 acc = {0.f, 0.f, 0.f, 0.f};
    for (int i = beg; i < end; i++) {
        int s = ssrc[i];
        float w = snorm[i];
        float4 v = hp[s * (FH / 4) + j];
        acc.x += v.x * w; acc.y += v.y * w; acc.z += v.z * w; acc.w += v.w * w;
    }
    float4 bb = ((const float4*)b1)[j];
    acc.x = fmaxf(acc.x + bb.x, 0.f);
    acc.y = fmaxf(acc.y + bb.y, 0.f);
    acc.z = fmaxf(acc.z + bb.z, 0.f);
    acc.w = fmaxf(acc.w + bb.w, 0.f);
    ((float4*)h)[node * (FH / 4) + j] = acc;
}

// GEMM2: h2[N][16] = h[N][128] @ W2[128][16]. Block: 256 thr = 16 rows x 16 cols.
__global__ __launch_bounds__(256) void GCN_gemm2_k(const float* __restrict__ h,
                                                   const float* __restrict__ W2,
                                                   float* __restrict__ h2, int N) {
    __shared__ float w2s[FH][FO];        // 8 KiB
    __shared__ float hs[16][FH + 4];     // pad 132 -> 16B-aligned rows, bank-spread
    int tid = threadIdx.x;
    #pragma unroll
    for (int j = 0; j < (FH * FO) / 256; j++) {
        int i = tid + j * 256;
        w2s[i >> 4][i & 15] = W2[i];
    }
    int row0 = blockIdx.x * 16;
    #pragma unroll
    for (int j = 0; j < (16 * FH) / 256; j++) {
        int i = tid + j * 256;
        int r = i >> 7, k = i & 127;
        int gr = row0 + r;
        hs[r][k] = (gr < N) ? h[gr * FH + k] : 0.f;
    }
    __syncthreads();
    int r = tid >> 4, f = tid & 15;
    float acc = 0.f;
    for (int k = 0; k < FH; k++) acc += hs[r][k] * w2s[k][f];
    int gr = row0 + r;
    if (gr < N) h2[gr * FO + f] = acc;
}

// AGG2 + bias + log_softmax fused. 16 lanes per node, shuffle reductions.
__global__ __launch_bounds__(256) void GCN_agg2_k(const float* __restrict__ h2,
                                                  const int* __restrict__ row_start,
                                                  const int* __restrict__ ssrc,
                                                  const float* __restrict__ snorm,
                                                  const float* __restrict__ b2,
                                                  float* __restrict__ out, int N) {
    int tid = threadIdx.x;
    int node = blockIdx.x * 16 + (tid >> 4);
    if (node >= N) return;
    int f = tid & 15;
    int beg = row_start[node], end = row_start[node + 1];
    float acc = 0.f;
    for (int i = beg; i < end; i++) {
        acc += h2[ssrc[i] * FO + f] * snorm[i];
    }
    float v = acc + b2[f];
    float mx = v;
    #pragma unroll
    for (int m = 8; m >= 1; m >>= 1) mx = fmaxf(mx, __shfl_xor(mx, m, 16));
    float e = expf(v - mx);
    float sum = e;
    #pragma unroll
    for (int m = 8; m >= 1; m >>= 1) sum += __shfl_xor(sum, m, 16);
    out[node * FO + f] = v - mx - logf(sum);
}

extern "C" void kernel_launch(void* const* d_in, const int* in_sizes, int n_in,
                              void* d_out, int out_size, void* d_ws, size_t ws_size,
                              hipStream_t stream) {
    (void)n_in; (void)out_size; (void)ws_size;
    const float* x  = (const float*)d_in[0];
    const int*   ed = (const int*)d_in[1];
    const float* W1 = (const float*)d_in[2];
    const float* b1 = (const float*)d_in[3];
    const float* W2 = (const float*)d_in[4];
    const float* b2 = (const float*)d_in[5];
    float* out = (float*)d_out;

    int N = in_sizes[0] / FIN;   // 50000
    int E = in_sizes[1] / 2;     // 800000
    int M = E + N;               // edges incl. self-loops

    // workspace carve-up (256B aligned)
    char* p = (char*)d_ws;
    auto take = [&](size_t bytes) -> char* {
        char* r = p;
        p += (bytes + 255) & ~(size_t)255;
        return r;
    };
    int*   count  = (int*)take((size_t)N * 4);
    int*   cursor = (int*)take((size_t)N * 4);
    int*   rs     = (int*)take((size_t)(N + 1) * 4);
    float* dinv   = (float*)take((size_t)N * 4);
    int*   ssrc   = (int*)take((size_t)M * 4);
    float* snorm  = (float*)take((size_t)M * 4);
    float* h1     = (float*)take((size_t)N * FH * 4);
    float* h      = (float*)take((size_t)N * FH * 4);
    float* h2     = (float*)take((size_t)N * FO * 4);

    GCN_zero_k<<<(N + 255) / 256, 256, 0, stream>>>(count, cursor, N);
    GCN_hist_k<<<(E + 255) / 256, 256, 0, stream>>>(ed, count, E);
    GCN_scan_k<<<1, 1024, 0, stream>>>(count, rs, dinv, N);
    GCN_fill_k<<<(M + 255) / 256, 256, 0, stream>>>(ed, rs, cursor, dinv, ssrc, snorm, E, N);
    GCN_gemm1_k<<<(N + G1_BR - 1) / G1_BR, 256, 0, stream>>>(x, W1, h1, N);
    GCN_agg1_k<<<((size_t)N * 32 + 255) / 256, 256, 0, stream>>>(h1, rs, ssrc, snorm, b1, h, N);
    GCN_gemm2_k<<<(N + 15) / 16, 256, 0, stream>>>(h, W2, h2, N);
    GCN_agg2_k<<<(N + 15) / 16, 256, 0, stream>>>(h2, rs, ssrc, snorm, b2, out, N);
}

// Round 2
// 275.794 us; speedup vs baseline: 1.3516x; 1.3516x over previous
//
#include <hip/hip_runtime.h>
#include <hip/hip_bf16.h>
#include <math.h>

// ---------------------------------------------------------------------------
// GCN 2-layer forward, fp32. Pipeline:
//   1) zero counters
//   2) histogram of dst (in-degree, excluding self-loop)
//   3) parallel scan: bsum_k (block partials) + scan2_k (offset+block scan)
//      -> row_start, dinv = rsqrt(deg+1)
//   4) counting-sort fill: CSR (sorted_src, sorted_norm) grouped by dst
//   5) GEMM1: h1 = x @ W1            (50000x256 @ 256x128, fp32 vector ALU)
//   6) AGG1:  h  = relu(gather-sum(h1[src]*norm) + b1)   [CSR gather, float4]
//   7) GEMM2: h2 = h @ W2            (50000x128 @ 128x16)
//   8) AGG2 + bias + log_softmax fused (16-lane shuffle reductions)
// ---------------------------------------------------------------------------

#define FIN 256
#define FH  128
#define FO  16
#define SCAN_CHUNK 1024   // elements per block in the scan kernels

__global__ __launch_bounds__(256) void GCN_zero_k(int* __restrict__ count,
                                                  int* __restrict__ cursor, int N) {
    int i = blockIdx.x * 256 + threadIdx.x;
    if (i < N) { count[i] = 0; cursor[i] = 0; }
}

__global__ __launch_bounds__(256) void GCN_hist_k(const int* __restrict__ edge,
                                                  int* __restrict__ count, int E) {
    int i = blockIdx.x * 256 + threadIdx.x;
    if (i < E) atomicAdd(&count[edge[E + i]], 1);
}

// Phase A: per-block partial sums of (count[v]+1) over 1024-element chunks.
__global__ __launch_bounds__(256) void GCN_bsum_k(const int* __restrict__ count,
                                                  int* __restrict__ bsum, int N) {
    int tid = threadIdx.x;
    int i0 = blockIdx.x * SCAN_CHUNK + tid * 4;
    int s = 0;
    if (i0 + 3 < N) {
        int4 c = *(const int4*)&count[i0];
        s = c.x + c.y + c.z + c.w + 4;
    } else {
        for (int j = 0; j < 4; j++)
            if (i0 + j < N) s += count[i0 + j] + 1;
    }
    __shared__ int red[256];
    red[tid] = s;
    __syncthreads();
    for (int st = 128; st > 0; st >>= 1) {
        if (tid < st) red[tid] += red[tid + st];
        __syncthreads();
    }
    if (tid == 0) bsum[blockIdx.x] = red[0];
}

// Phase B+C: each block sums bsum[0..b) for its offset (parallel across
// blocks), block-scans its 1024 elements, writes row_start + dinv.
__global__ __launch_bounds__(256) void GCN_scan2_k(const int* __restrict__ count,
                                                   const int* __restrict__ bsum,
                                                   int* __restrict__ row_start,
                                                   float* __restrict__ dinv, int N) {
    int tid = threadIdx.x;
    int b = blockIdx.x;
    int i0 = b * SCAN_CHUNK + tid * 4;

    int v0 = 0, v1 = 0, v2 = 0, v3 = 0;
    if (i0 + 3 < N) {
        int4 c = *(const int4*)&count[i0];
        v0 = c.x + 1; v1 = c.y + 1; v2 = c.z + 1; v3 = c.w + 1;
    } else {
        if (i0 + 0 < N) v0 = count[i0 + 0] + 1;
        if (i0 + 1 < N) v1 = count[i0 + 1] + 1;
        if (i0 + 2 < N) v2 = count[i0 + 2] + 1;
        if (i0 + 3 < N) v3 = count[i0 + 3] + 1;
    }
    int lsum = v0 + v1 + v2 + v3;

    // block offset = sum of bsum over preceding blocks
    __shared__ int red[256];
    int offp = 0;
    for (int t = tid; t < b; t += 256) offp += bsum[t];
    red[tid] = offp;
    __syncthreads();
    for (int st = 128; st > 0; st >>= 1) {
        if (tid < st) red[tid] += red[tid + st];
        __syncthreads();
    }
    int blockOff = red[0];
    __syncthreads();

    // Hillis-Steele inclusive scan of per-thread sums
    __shared__ int ssum[256];
    ssum[tid] = lsum;
    __syncthreads();
    for (int off = 1; off < 256; off <<= 1) {
        int t = (tid >= off) ? ssum[tid - off] : 0;
        __syncthreads();
        ssum[tid] += t;
        __syncthreads();
    }
    int r = blockOff + (tid == 0 ? 0 : ssum[tid - 1]);

    if (i0 + 0 < N) { row_start[i0 + 0] = r; dinv[i0 + 0] = rsqrtf((float)v0); r += v0; }
    if (i0 + 1 < N) { row_start[i0 + 1] = r; dinv[i0 + 1] = rsqrtf((float)v1); r += v1; }
    if (i0 + 2 < N) { row_start[i0 + 2] = r; dinv[i0 + 2] = rsqrtf((float)v2); r += v2; }
    if (i0 + 3 < N) { row_start[i0 + 3] = r; dinv[i0 + 3] = rsqrtf((float)v3); r += v3; }

    if (b == gridDim.x - 1 && tid == 255) row_start[N] = blockOff + ssum[255];
}

__global__ __launch_bounds__(256) void GCN_fill_k(const int* __restrict__ edge,
                                                  const int* __restrict__ row_start,
                                                  int* __restrict__ cursor,
                                                  const float* __restrict__ dinv,
                                                  int* __restrict__ ssrc,
                                                  float* __restrict__ snorm,
                                                  int E, int N) {
    int i = blockIdx.x * 256 + threadIdx.x;
    if (i < E) {
        int s = edge[i];
        int d = edge[E + i];
        int p = atomicAdd(&cursor[d], 1);
        int idx = row_start[d] + p;
        ssrc[idx] = s;
        snorm[idx] = dinv[s] * dinv[d];
    } else if (i < E + N) {
        int v = i - E;
        int p = atomicAdd(&cursor[v], 1);
        int idx = row_start[v] + p;
        ssrc[idx] = v;
        float q = dinv[v];
        snorm[idx] = q * q;
    }
}

// GEMM1: h1[N][128] = x[N][256] @ W1[256][128]. Block: 256 thr, 32 rows.
// 4x4 register tile per thread. K staged in 64-chunks.
#define G1_BR 32
#define G1_KC 64
__global__ __launch_bounds__(256) void GCN_gemm1_k(const float* __restrict__ x,
                                                   const float* __restrict__ W1,
                                                   float* __restrict__ h1, int N) {
    __shared__ __align__(16) float wsh[G1_KC][FH];       // 32 KiB
    __shared__ __align__(16) float xs[G1_BR][G1_KC + 1]; // pad 65 -> bank-spread
    int tid = threadIdx.x;
    int row0 = blockIdx.x * G1_BR;
    int tc = tid & 31;   // col quad: cols 4*tc..4*tc+3
    int tr = tid >> 5;   // row quad: rows 4*tr..4*tr+3
    float acc00 = 0, acc01 = 0, acc02 = 0, acc03 = 0;
    float acc10 = 0, acc11 = 0, acc12 = 0, acc13 = 0;
    float acc20 = 0, acc21 = 0, acc22 = 0, acc23 = 0;
    float acc30 = 0, acc31 = 0, acc32 = 0, acc33 = 0;

    for (int kc = 0; kc < FIN; kc += G1_KC) {
        #pragma unroll
        for (int j = 0; j < (G1_KC * FH) / 256; j++) {
            int i = tid + j * 256;
            wsh[i >> 7][i & 127] = W1[(kc + (i >> 7)) * FH + (i & 127)];
        }
        #pragma unroll
        for (int j = 0; j < (G1_BR * G1_KC) / 256; j++) {
            int i = tid + j * 256;
            int r = i >> 6, k = i & 63;
            int gr = row0 + r;
            xs[r][k] = (gr < N) ? x[gr * FIN + kc + k] : 0.f;
        }
        __syncthreads();
        for (int k = 0; k < G1_KC; k++) {
            float4 wv = *(const float4*)&wsh[k][tc * 4];
            float x0 = xs[tr * 4 + 0][k];
            float x1 = xs[tr * 4 + 1][k];
            float x2 = xs[tr * 4 + 2][k];
            float x3 = xs[tr * 4 + 3][k];
            acc00 += x0 * wv.x; acc01 += x0 * wv.y; acc02 += x0 * wv.z; acc03 += x0 * wv.w;
            acc10 += x1 * wv.x; acc11 += x1 * wv.y; acc12 += x1 * wv.z; acc13 += x1 * wv.w;
            acc20 += x2 * wv.x; acc21 += x2 * wv.y; acc22 += x2 * wv.z; acc23 += x2 * wv.w;
            acc30 += x3 * wv.x; acc31 += x3 * wv.y; acc32 += x3 * wv.z; acc33 += x3 * wv.w;
        }
        __syncthreads();
    }
    int gr0 = row0 + tr * 4;
    if (gr0 + 0 < N) { float4 o = {acc00, acc01, acc02, acc03}; *(float4*)&h1[(gr0 + 0) * FH + tc * 4] = o; }
    if (gr0 + 1 < N) { float4 o = {acc10, acc11, acc12, acc13}; *(float4*)&h1[(gr0 + 1) * FH + tc * 4] = o; }
    if (gr0 + 2 < N) { float4 o = {acc20, acc21, acc22, acc23}; *(float4*)&h1[(gr0 + 2) * FH + tc * 4] = o; }
    if (gr0 + 3 < N) { float4 o = {acc30, acc31, acc32, acc33}; *(float4*)&h1[(gr0 + 3) * FH + tc * 4] = o; }
}

// AGG1: h[node][f] = relu(b1[f] + sum_{e in row(node)} h1[src_e][f]*norm_e)
__global__ __launch_bounds__(256) void GCN_agg1_k(const float* __restrict__ h1,
                                                  const int* __restrict__ row_start,
                                                  const int* __restrict__ ssrc,
                                                  const float* __restrict__ snorm,
                                                  const float* __restrict__ b1,
                                                  float* __restrict__ h, int N) {
    int gid = blockIdx.x * 256 + threadIdx.x;
    int node = gid >> 5;
    if (node >= N) return;
    int j = gid & 31;
    int beg = row_start[node], end = row_start[node + 1];
    const float4* hp = (const float4*)h1;
    float4 acc = {0.f, 0.f, 0.f, 0.f};
    for (int i = beg; i < end; i++) {
        int s = ssrc[i];
        float w = snorm[i];
        float4 v = hp[s * (FH / 4) + j];
        acc.x += v.x * w; acc.y += v.y * w; acc.z += v.z * w; acc.w += v.w * w;
    }
    float4 bb = ((const float4*)b1)[j];
    acc.x = fmaxf(acc.x + bb.x, 0.f);
    acc.y = fmaxf(acc.y + bb.y, 0.f);
    acc.z = fmaxf(acc.z + bb.z, 0.f);
    acc.w = fmaxf(acc.w + bb.w, 0.f);
    ((float4*)h)[node * (FH / 4) + j] = acc;
}

// GEMM2: h2[N][16] = h[N][128] @ W2[128][16]. Block: 256 thr = 16 rows x 16 cols.
__global__ __launch_bounds__(256) void GCN_gemm2_k(const float* __restrict__ h,
                                                   const float* __restrict__ W2,
                                                   float* __restrict__ h2, int N) {
    __shared__ float w2s[FH][FO];        // 8 KiB
    __shared__ float hs[16][FH + 4];
    int tid = threadIdx.x;
    #pragma unroll
    for (int j = 0; j < (FH * FO) / 256; j++) {
        int i = tid + j * 256;
        w2s[i >> 4][i & 15] = W2[i];
    }
    int row0 = blockIdx.x * 16;
    #pragma unroll
    for (int j = 0; j < (16 * FH) / 256; j++) {
        int i = tid + j * 256;
        int r = i >> 7, k = i & 127;
        int gr = row0 + r;
        hs[r][k] = (gr < N) ? h[gr * FH + k] : 0.f;
    }
    __syncthreads();
    int r = tid >> 4, f = tid & 15;
    float acc = 0.f;
    for (int k = 0; k < FH; k++) acc += hs[r][k] * w2s[k][f];
    int gr = row0 + r;
    if (gr < N) h2[gr * FO + f] = acc;
}

// AGG2 + bias + log_softmax fused. 16 lanes per node, shuffle reductions.
__global__ __launch_bounds__(256) void GCN_agg2_k(const float* __restrict__ h2,
                                                  const int* __restrict__ row_start,
                                                  const int* __restrict__ ssrc,
                                                  const float* __restrict__ snorm,
                                                  const float* __restrict__ b2,
                                                  float* __restrict__ out, int N) {
    int tid = threadIdx.x;
    int node = blockIdx.x * 16 + (tid >> 4);
    if (node >= N) return;
    int f = tid & 15;
    int beg = row_start[node], end = row_start[node + 1];
    float acc = 0.f;
    for (int i = beg; i < end; i++) {
        acc += h2[ssrc[i] * FO + f] * snorm[i];
    }
    float v = acc + b2[f];
    float mx = v;
    #pragma unroll
    for (int m = 8; m >= 1; m >>= 1) mx = fmaxf(mx, __shfl_xor(mx, m, 16));
    float e = expf(v - mx);
    float sum = e;
    #pragma unroll
    for (int m = 8; m >= 1; m >>= 1) sum += __shfl_xor(sum, m, 16);
    out[node * FO + f] = v - mx - logf(sum);
}

extern "C" void kernel_launch(void* const* d_in, const int* in_sizes, int n_in,
                              void* d_out, int out_size, void* d_ws, size_t ws_size,
                              hipStream_t stream) {
    (void)n_in; (void)out_size; (void)ws_size;
    const float* x  = (const float*)d_in[0];
    const int*   ed = (const int*)d_in[1];
    const float* W1 = (const float*)d_in[2];
    const float* b1 = (const float*)d_in[3];
    const float* W2 = (const float*)d_in[4];
    const float* b2 = (const float*)d_in[5];
    float* out = (float*)d_out;

    int N = in_sizes[0] / FIN;   // 50000
    int E = in_sizes[1] / 2;     // 800000
    int M = E + N;               // edges incl. self-loops
    int nScanBlocks = (N + SCAN_CHUNK - 1) / SCAN_CHUNK;  // 49

    char* p = (char*)d_ws;
    auto take = [&](size_t bytes) -> char* {
        char* r = p;
        p += (bytes + 255) & ~(size_t)255;
        return r;
    };
    int*   count  = (int*)take((size_t)N * 4);
    int*   cursor = (int*)take((size_t)N * 4);
    int*   rs     = (int*)take((size_t)(N + 1) * 4);
    float* dinv   = (float*)take((size_t)N * 4);
    int*   bsum   = (int*)take((size_t)nScanBlocks * 4);
    int*   ssrc   = (int*)take((size_t)M * 4);
    float* snorm  = (float*)take((size_t)M * 4);
    float* h1     = (float*)take((size_t)N * FH * 4);
    float* h      = (float*)take((size_t)N * FH * 4);
    float* h2     = (float*)take((size_t)N * FO * 4);

    GCN_zero_k<<<(N + 255) / 256, 256, 0, stream>>>(count, cursor, N);
    GCN_hist_k<<<(E + 255) / 256, 256, 0, stream>>>(ed, count, E);
    GCN_bsum_k<<<nScanBlocks, 256, 0, stream>>>(count, bsum, N);
    GCN_scan2_k<<<nScanBlocks, 256, 0, stream>>>(count, bsum, rs, dinv, N);
    GCN_fill_k<<<(M + 255) / 256, 256, 0, stream>>>(ed, rs, cursor, dinv, ssrc, snorm, E, N);
    GCN_gemm1_k<<<(N + G1_BR - 1) / G1_BR, 256, 0, stream>>>(x, W1, h1, N);
    GCN_agg1_k<<<((size_t)N * 32 + 255) / 256, 256, 0, stream>>>(h1, rs, ssrc, snorm, b1, h, N);
    GCN_gemm2_k<<<(N + 15) / 16, 256, 0, stream>>>(h, W2, h2, N);
    GCN_agg2_k<<<(N + 15) / 16, 256, 0, stream>>>(h2, rs, ssrc, snorm, b2, out, N);
}

// Round 3
// 259.142 us; speedup vs baseline: 1.4385x; 1.0643x over previous
//
#include <hip/hip_runtime.h>
#include <hip/hip_bf16.h>
#include <math.h>

// ---------------------------------------------------------------------------
// GCN 2-layer forward, fp32. Pipeline:
//   1) zero counters
//   2) histogram of dst (in-degree, excluding self-loop)
//   3) parallel scan: bsum_k (block partials) + scan2_k (offset+block scan)
//   4) counting-sort fill: CSR (sorted_src, sorted_norm) grouped by dst
//   5) GEMM1: h1 = x @ W1   (64x128 block tile, 8x4 reg tile, transposed x LDS)
//   6) AGG1:  h  = relu(gather-sum(h1[src]*norm) + b1)   [CSR gather, float4]
//   7) GEMM2: h2 = h @ W2            (50000x128 @ 128x16)
//   8) AGG2 + bias + log_softmax fused (16-lane shuffle reductions)
// ---------------------------------------------------------------------------

#define FIN 256
#define FH  128
#define FO  16
#define SCAN_CHUNK 1024   // elements per block in the scan kernels

__global__ __launch_bounds__(256) void GCN_zero_k(int* __restrict__ count,
                                                  int* __restrict__ cursor, int N) {
    int i = blockIdx.x * 256 + threadIdx.x;
    if (i < N) { count[i] = 0; cursor[i] = 0; }
}

__global__ __launch_bounds__(256) void GCN_hist_k(const int* __restrict__ edge,
                                                  int* __restrict__ count, int E) {
    int i = blockIdx.x * 256 + threadIdx.x;
    if (i < E) atomicAdd(&count[edge[E + i]], 1);
}

// Phase A: per-block partial sums of (count[v]+1) over 1024-element chunks.
__global__ __launch_bounds__(256) void GCN_bsum_k(const int* __restrict__ count,
                                                  int* __restrict__ bsum, int N) {
    int tid = threadIdx.x;
    int i0 = blockIdx.x * SCAN_CHUNK + tid * 4;
    int s = 0;
    if (i0 + 3 < N) {
        int4 c = *(const int4*)&count[i0];
        s = c.x + c.y + c.z + c.w + 4;
    } else {
        for (int j = 0; j < 4; j++)
            if (i0 + j < N) s += count[i0 + j] + 1;
    }
    __shared__ int red[256];
    red[tid] = s;
    __syncthreads();
    for (int st = 128; st > 0; st >>= 1) {
        if (tid < st) red[tid] += red[tid + st];
        __syncthreads();
    }
    if (tid == 0) bsum[blockIdx.x] = red[0];
}

// Phase B+C: each block sums bsum[0..b) for its offset, block-scans its
// 1024 elements, writes row_start + dinv.
__global__ __launch_bounds__(256) void GCN_scan2_k(const int* __restrict__ count,
                                                   const int* __restrict__ bsum,
                                                   int* __restrict__ row_start,
                                                   float* __restrict__ dinv, int N) {
    int tid = threadIdx.x;
    int b = blockIdx.x;
    int i0 = b * SCAN_CHUNK + tid * 4;

    int v0 = 0, v1 = 0, v2 = 0, v3 = 0;
    if (i0 + 3 < N) {
        int4 c = *(const int4*)&count[i0];
        v0 = c.x + 1; v1 = c.y + 1; v2 = c.z + 1; v3 = c.w + 1;
    } else {
        if (i0 + 0 < N) v0 = count[i0 + 0] + 1;
        if (i0 + 1 < N) v1 = count[i0 + 1] + 1;
        if (i0 + 2 < N) v2 = count[i0 + 2] + 1;
        if (i0 + 3 < N) v3 = count[i0 + 3] + 1;
    }
    int lsum = v0 + v1 + v2 + v3;

    __shared__ int red[256];
    int offp = 0;
    for (int t = tid; t < b; t += 256) offp += bsum[t];
    red[tid] = offp;
    __syncthreads();
    for (int st = 128; st > 0; st >>= 1) {
        if (tid < st) red[tid] += red[tid + st];
        __syncthreads();
    }
    int blockOff = red[0];
    __syncthreads();

    __shared__ int ssum[256];
    ssum[tid] = lsum;
    __syncthreads();
    for (int off = 1; off < 256; off <<= 1) {
        int t = (tid >= off) ? ssum[tid - off] : 0;
        __syncthreads();
        ssum[tid] += t;
        __syncthreads();
    }
    int r = blockOff + (tid == 0 ? 0 : ssum[tid - 1]);

    if (i0 + 0 < N) { row_start[i0 + 0] = r; dinv[i0 + 0] = rsqrtf((float)v0); r += v0; }
    if (i0 + 1 < N) { row_start[i0 + 1] = r; dinv[i0 + 1] = rsqrtf((float)v1); r += v1; }
    if (i0 + 2 < N) { row_start[i0 + 2] = r; dinv[i0 + 2] = rsqrtf((float)v2); r += v2; }
    if (i0 + 3 < N) { row_start[i0 + 3] = r; dinv[i0 + 3] = rsqrtf((float)v3); r += v3; }

    if (b == gridDim.x - 1 && tid == 255) row_start[N] = blockOff + ssum[255];
}

__global__ __launch_bounds__(256) void GCN_fill_k(const int* __restrict__ edge,
                                                  const int* __restrict__ row_start,
                                                  int* __restrict__ cursor,
                                                  const float* __restrict__ dinv,
                                                  int* __restrict__ ssrc,
                                                  float* __restrict__ snorm,
                                                  int E, int N) {
    int i = blockIdx.x * 256 + threadIdx.x;
    if (i < E) {
        int s = edge[i];
        int d = edge[E + i];
        int p = atomicAdd(&cursor[d], 1);
        int idx = row_start[d] + p;
        ssrc[idx] = s;
        snorm[idx] = dinv[s] * dinv[d];
    } else if (i < E + N) {
        int v = i - E;
        int p = atomicAdd(&cursor[v], 1);
        int idx = row_start[v] + p;
        ssrc[idx] = v;
        float q = dinv[v];
        snorm[idx] = q * q;
    }
}

// GEMM1: h1[N][128] = x[N][256] @ W1[256][128].
// Block: 256 thr -> 64 rows x 128 cols. Reg tile 8x4. K chunks of 64.
// x tile stored TRANSPOSED in LDS (xs_t[k][row]) so the 8 row-values load as
// two ds_read_b128 broadcast across the 32 lanes that share tr.
#define G1_BR 64
#define G1_KC 64
#define G1_XP 68   // padded row stride for xs_t (keeps 16B alignment, spreads banks)
__global__ __launch_bounds__(256) void GCN_gemm1_k(const float* __restrict__ x,
                                                   const float* __restrict__ W1,
                                                   float* __restrict__ h1, int N) {
    __shared__ __align__(16) float wsh[G1_KC][FH];      // 32 KiB
    __shared__ __align__(16) float xs_t[G1_KC][G1_XP];  // 17 KiB, [k][row]
    int tid = threadIdx.x;
    int row0 = blockIdx.x * G1_BR;
    int tc = tid & 31;   // col quad: cols 4*tc..4*tc+3
    int tr = tid >> 5;   // row octet: rows 8*tr..8*tr+7
    float acc[8][4];
    #pragma unroll
    for (int i = 0; i < 8; i++)
        #pragma unroll
        for (int j = 0; j < 4; j++) acc[i][j] = 0.f;

    for (int kc = 0; kc < FIN; kc += G1_KC) {
        // stage W chunk [64][128]: 2048 float4 / 256 thr = 8 each, coalesced
        #pragma unroll
        for (int j = 0; j < (G1_KC * FH) / (256 * 4); j++) {
            int u = tid + j * 256;          // float4 unit
            int wr = u >> 5, wc = u & 31;   // 32 float4 per row
            float4 v = *(const float4*)&W1[(kc + wr) * FH + wc * 4];
            *(float4*)&wsh[wr][wc * 4] = v;
        }
        // stage x tile transposed: [64 rows][64 k] -> xs_t[k][row]
        #pragma unroll
        for (int j = 0; j < (G1_BR * G1_KC) / (256 * 4); j++) {
            int u = tid + j * 256;          // float4 unit
            int r = u >> 4, kq = u & 15;    // 16 float4 per row
            int gr = row0 + r;
            float4 v = (gr < N) ? *(const float4*)&x[gr * FIN + kc + kq * 4]
                                : make_float4(0.f, 0.f, 0.f, 0.f);
            xs_t[kq * 4 + 0][r] = v.x;
            xs_t[kq * 4 + 1][r] = v.y;
            xs_t[kq * 4 + 2][r] = v.z;
            xs_t[kq * 4 + 3][r] = v.w;
        }
        __syncthreads();
        #pragma unroll 4
        for (int k = 0; k < G1_KC; k++) {
            float4 wv = *(const float4*)&wsh[k][tc * 4];
            float4 xa = *(const float4*)&xs_t[k][tr * 8];
            float4 xb = *(const float4*)&xs_t[k][tr * 8 + 4];
            float xr[8] = {xa.x, xa.y, xa.z, xa.w, xb.x, xb.y, xb.z, xb.w};
            #pragma unroll
            for (int i = 0; i < 8; i++) {
                acc[i][0] += xr[i] * wv.x;
                acc[i][1] += xr[i] * wv.y;
                acc[i][2] += xr[i] * wv.z;
                acc[i][3] += xr[i] * wv.w;
            }
        }
        __syncthreads();
    }
    #pragma unroll
    for (int i = 0; i < 8; i++) {
        int gr = row0 + tr * 8 + i;
        if (gr < N) {
            float4 o = {acc[i][0], acc[i][1], acc[i][2], acc[i][3]};
            *(float4*)&h1[gr * FH + tc * 4] = o;
        }
    }
}

// AGG1: h[node][f] = relu(b1[f] + sum_{e in row(node)} h1[src_e][f]*norm_e)
__global__ __launch_bounds__(256) void GCN_agg1_k(const float* __restrict__ h1,
                                                  const int* __restrict__ row_start,
                                                  const int* __restrict__ ssrc,
                                                  const float* __restrict__ snorm,
                                                  const float* __restrict__ b1,
                                                  float* __restrict__ h, int N) {
    int gid = blockIdx.x * 256 + threadIdx.x;
    int node = gid >> 5;
    if (node >= N) return;
    int j = gid & 31;
    int beg = row_start[node], end = row_start[node + 1];
    const float4* hp = (const float4*)h1;
    float4 acc = {0.f, 0.f, 0.f, 0.f};
    for (int i = beg; i < end; i++) {
        int s = ssrc[i];
        float w = snorm[i];
        float4 v = hp[s * (FH / 4) + j];
        acc.x += v.x * w; acc.y += v.y * w; acc.z += v.z * w; acc.w += v.w * w;
    }
    float4 bb = ((const float4*)b1)[j];
    acc.x = fmaxf(acc.x + bb.x, 0.f);
    acc.y = fmaxf(acc.y + bb.y, 0.f);
    acc.z = fmaxf(acc.z + bb.z, 0.f);
    acc.w = fmaxf(acc.w + bb.w, 0.f);
    ((float4*)h)[node * (FH / 4) + j] = acc;
}

// GEMM2: h2[N][16] = h[N][128] @ W2[128][16]. Block: 256 thr = 16 rows x 16 cols.
__global__ __launch_bounds__(256) void GCN_gemm2_k(const float* __restrict__ h,
                                                   const float* __restrict__ W2,
                                                   float* __restrict__ h2, int N) {
    __shared__ float w2s[FH][FO];        // 8 KiB
    __shared__ float hs[16][FH + 4];
    int tid = threadIdx.x;
    #pragma unroll
    for (int j = 0; j < (FH * FO) / 256; j++) {
        int i = tid + j * 256;
        w2s[i >> 4][i & 15] = W2[i];
    }
    int row0 = blockIdx.x * 16;
    #pragma unroll
    for (int j = 0; j < (16 * FH) / 256; j++) {
        int i = tid + j * 256;
        int r = i >> 7, k = i & 127;
        int gr = row0 + r;
        hs[r][k] = (gr < N) ? h[gr * FH + k] : 0.f;
    }
    __syncthreads();
    int r = tid >> 4, f = tid & 15;
    float acc = 0.f;
    for (int k = 0; k < FH; k++) acc += hs[r][k] * w2s[k][f];
    int gr = row0 + r;
    if (gr < N) h2[gr * FO + f] = acc;
}

// AGG2 + bias + log_softmax fused. 16 lanes per node, shuffle reductions.
__global__ __launch_bounds__(256) void GCN_agg2_k(const float* __restrict__ h2,
                                                  const int* __restrict__ row_start,
                                                  const int* __restrict__ ssrc,
                                                  const float* __restrict__ snorm,
                                                  const float* __restrict__ b2,
                                                  float* __restrict__ out, int N) {
    int tid = threadIdx.x;
    int node = blockIdx.x * 16 + (tid >> 4);
    if (node >= N) return;
    int f = tid & 15;
    int beg = row_start[node], end = row_start[node + 1];
    float acc = 0.f;
    for (int i = beg; i < end; i++) {
        acc += h2[ssrc[i] * FO + f] * snorm[i];
    }
    float v = acc + b2[f];
    float mx = v;
    #pragma unroll
    for (int m = 8; m >= 1; m >>= 1) mx = fmaxf(mx, __shfl_xor(mx, m, 16));
    float e = expf(v - mx);
    float sum = e;
    #pragma unroll
    for (int m = 8; m >= 1; m >>= 1) sum += __shfl_xor(sum, m, 16);
    out[node * FO + f] = v - mx - logf(sum);
}

extern "C" void kernel_launch(void* const* d_in, const int* in_sizes, int n_in,
                              void* d_out, int out_size, void* d_ws, size_t ws_size,
                              hipStream_t stream) {
    (void)n_in; (void)out_size; (void)ws_size;
    const float* x  = (const float*)d_in[0];
    const int*   ed = (const int*)d_in[1];
    const float* W1 = (const float*)d_in[2];
    const float* b1 = (const float*)d_in[3];
    const float* W2 = (const float*)d_in[4];
    const float* b2 = (const float*)d_in[5];
    float* out = (float*)d_out;

    int N = in_sizes[0] / FIN;   // 50000
    int E = in_sizes[1] / 2;     // 800000
    int M = E + N;               // edges incl. self-loops
    int nScanBlocks = (N + SCAN_CHUNK - 1) / SCAN_CHUNK;  // 49

    char* p = (char*)d_ws;
    auto take = [&](size_t bytes) -> char* {
        char* r = p;
        p += (bytes + 255) & ~(size_t)255;
        return r;
    };
    int*   count  = (int*)take((size_t)N * 4);
    int*   cursor = (int*)take((size_t)N * 4);
    int*   rs     = (int*)take((size_t)(N + 1) * 4);
    float* dinv   = (float*)take((size_t)N * 4);
    int*   bsum   = (int*)take((size_t)nScanBlocks * 4);
    int*   ssrc   = (int*)take((size_t)M * 4);
    float* snorm  = (float*)take((size_t)M * 4);
    float* h1     = (float*)take((size_t)N * FH * 4);
    float* h      = (float*)take((size_t)N * FH * 4);
    float* h2     = (float*)take((size_t)N * FO * 4);

    GCN_zero_k<<<(N + 255) / 256, 256, 0, stream>>>(count, cursor, N);
    GCN_hist_k<<<(E + 255) / 256, 256, 0, stream>>>(ed, count, E);
    GCN_bsum_k<<<nScanBlocks, 256, 0, stream>>>(count, bsum, N);
    GCN_scan2_k<<<nScanBlocks, 256, 0, stream>>>(count, bsum, rs, dinv, N);
    GCN_fill_k<<<(M + 255) / 256, 256, 0, stream>>>(ed, rs, cursor, dinv, ssrc, snorm, E, N);
    GCN_gemm1_k<<<(N + G1_BR - 1) / G1_BR, 256, 0, stream>>>(x, W1, h1, N);
    GCN_agg1_k<<<((size_t)N * 32 + 255) / 256, 256, 0, stream>>>(h1, rs, ssrc, snorm, b1, h, N);
    GCN_gemm2_k<<<(N + 15) / 16, 256, 0, stream>>>(h, W2, h2, N);
    GCN_agg2_k<<<(N + 15) / 16, 256, 0, stream>>>(h2, rs, ssrc, snorm, b2, out, N);
}

// Round 4
// 249.715 us; speedup vs baseline: 1.4928x; 1.0377x over previous
//
#include <hip/hip_runtime.h>
#include <hip/hip_bf16.h>
#include <math.h>

// ---------------------------------------------------------------------------
// GCN 2-layer forward, fp32 compute, bf16 h1 intermediate. Pipeline:
//   1) zero counters
//   2) histogram of dst (in-degree, excluding self-loop)
//   3) parallel scan: bsum_k + scan2_k -> row_start, dinv
//   4) counting-sort fill: CSR (sorted_src, sorted_norm) grouped by dst
//   5) GEMM1: h1(bf16) = x @ W1   (128x128 tile, 8x8 reg tile, LDS transpose)
//   6) AGG1:  h(f32) = relu(gather-sum(h1[src]*norm) + b1)  [bf16 gather]
//   7) GEMM2: h2 = h @ W2
//   8) AGG2 + bias + log_softmax fused
// ---------------------------------------------------------------------------

#define FIN 256
#define FH  128
#define FO  16
#define SCAN_CHUNK 1024

typedef unsigned int uint;
typedef unsigned short ushort;

static __device__ __forceinline__ ushort f2bf(float f) {
    __hip_bfloat16 b = __float2bfloat16(f);
    return *reinterpret_cast<ushort*>(&b);
}

__global__ __launch_bounds__(256) void GCN_zero_k(int* __restrict__ count,
                                                  int* __restrict__ cursor, int N) {
    int i = blockIdx.x * 256 + threadIdx.x;
    if (i < N) { count[i] = 0; cursor[i] = 0; }
}

__global__ __launch_bounds__(256) void GCN_hist_k(const int* __restrict__ edge,
                                                  int* __restrict__ count, int E) {
    int i = blockIdx.x * 256 + threadIdx.x;
    if (i < E) atomicAdd(&count[edge[E + i]], 1);
}

__global__ __launch_bounds__(256) void GCN_bsum_k(const int* __restrict__ count,
                                                  int* __restrict__ bsum, int N) {
    int tid = threadIdx.x;
    int i0 = blockIdx.x * SCAN_CHUNK + tid * 4;
    int s = 0;
    if (i0 + 3 < N) {
        int4 c = *(const int4*)&count[i0];
        s = c.x + c.y + c.z + c.w + 4;
    } else {
        for (int j = 0; j < 4; j++)
            if (i0 + j < N) s += count[i0 + j] + 1;
    }
    __shared__ int red[256];
    red[tid] = s;
    __syncthreads();
    for (int st = 128; st > 0; st >>= 1) {
        if (tid < st) red[tid] += red[tid + st];
        __syncthreads();
    }
    if (tid == 0) bsum[blockIdx.x] = red[0];
}

__global__ __launch_bounds__(256) void GCN_scan2_k(const int* __restrict__ count,
                                                   const int* __restrict__ bsum,
                                                   int* __restrict__ row_start,
                                                   float* __restrict__ dinv, int N) {
    int tid = threadIdx.x;
    int b = blockIdx.x;
    int i0 = b * SCAN_CHUNK + tid * 4;

    int v0 = 0, v1 = 0, v2 = 0, v3 = 0;
    if (i0 + 3 < N) {
        int4 c = *(const int4*)&count[i0];
        v0 = c.x + 1; v1 = c.y + 1; v2 = c.z + 1; v3 = c.w + 1;
    } else {
        if (i0 + 0 < N) v0 = count[i0 + 0] + 1;
        if (i0 + 1 < N) v1 = count[i0 + 1] + 1;
        if (i0 + 2 < N) v2 = count[i0 + 2] + 1;
        if (i0 + 3 < N) v3 = count[i0 + 3] + 1;
    }
    int lsum = v0 + v1 + v2 + v3;

    __shared__ int red[256];
    int offp = 0;
    for (int t = tid; t < b; t += 256) offp += bsum[t];
    red[tid] = offp;
    __syncthreads();
    for (int st = 128; st > 0; st >>= 1) {
        if (tid < st) red[tid] += red[tid + st];
        __syncthreads();
    }
    int blockOff = red[0];
    __syncthreads();

    __shared__ int ssum[256];
    ssum[tid] = lsum;
    __syncthreads();
    for (int off = 1; off < 256; off <<= 1) {
        int t = (tid >= off) ? ssum[tid - off] : 0;
        __syncthreads();
        ssum[tid] += t;
        __syncthreads();
    }
    int r = blockOff + (tid == 0 ? 0 : ssum[tid - 1]);

    if (i0 + 0 < N) { row_start[i0 + 0] = r; dinv[i0 + 0] = rsqrtf((float)v0); r += v0; }
    if (i0 + 1 < N) { row_start[i0 + 1] = r; dinv[i0 + 1] = rsqrtf((float)v1); r += v1; }
    if (i0 + 2 < N) { row_start[i0 + 2] = r; dinv[i0 + 2] = rsqrtf((float)v2); r += v2; }
    if (i0 + 3 < N) { row_start[i0 + 3] = r; dinv[i0 + 3] = rsqrtf((float)v3); r += v3; }

    if (b == gridDim.x - 1 && tid == 255) row_start[N] = blockOff + ssum[255];
}

__global__ __launch_bounds__(256) void GCN_fill_k(const int* __restrict__ edge,
                                                  const int* __restrict__ row_start,
                                                  int* __restrict__ cursor,
                                                  const float* __restrict__ dinv,
                                                  int* __restrict__ ssrc,
                                                  float* __restrict__ snorm,
                                                  int E, int N) {
    int i = blockIdx.x * 256 + threadIdx.x;
    if (i < E) {
        int s = edge[i];
        int d = edge[E + i];
        int p = atomicAdd(&cursor[d], 1);
        int idx = row_start[d] + p;
        ssrc[idx] = s;
        snorm[idx] = dinv[s] * dinv[d];
    } else if (i < E + N) {
        int v = i - E;
        int p = atomicAdd(&cursor[v], 1);
        int idx = row_start[v] + p;
        ssrc[idx] = v;
        float q = dinv[v];
        snorm[idx] = q * q;
    }
}

// GEMM1: h1(bf16)[N][128] = x[N][256] @ W1[256][128].
// 256 thr -> 128x128 tile, 8x8 reg tile. K chunks of 32.
// x tile transposed into LDS via 4x4 micro-tiles (float4 in, float4 out).
#define G1_BR 128
#define G1_KC 32
#define G1_WP 132   // wsh row stride (floats)
#define G1_XP 132   // xs_t row stride (floats)
__global__ __launch_bounds__(256, 4) void GCN_gemm1_k(const float* __restrict__ x,
                                                      const float* __restrict__ W1,
                                                      ushort* __restrict__ h1,
                                                      int N) {
    __shared__ __align__(16) float wsh[G1_KC * G1_WP];   // 16.5 KiB
    __shared__ __align__(16) float xs_t[G1_KC * G1_XP];  // 16.5 KiB
    int tid = threadIdx.x;
    int row0 = blockIdx.x * G1_BR;
    int tc = tid & 15;    // col octet: cols 8*tc
    int tr = tid >> 4;    // row octet: rows 8*tr
    int qh = tid & 7;     // staging: k-quad
    int rh = tid >> 3;    // staging: row-quad (0..31)
    float acc[8][8];
    #pragma unroll
    for (int i = 0; i < 8; i++)
        #pragma unroll
        for (int j = 0; j < 8; j++) acc[i][j] = 0.f;

    for (int kc = 0; kc < FIN; kc += G1_KC) {
        // stage W chunk [32][128]: 1024 float4 / 256 thr = 4 each, coalesced
        #pragma unroll
        for (int j = 0; j < 4; j++) {
            int u = tid + j * 256;
            int wr = u >> 5, wc = u & 31;
            float4 v = *(const float4*)&W1[(kc + wr) * FH + wc * 4];
            *(float4*)&wsh[wr * G1_WP + wc * 4] = v;
        }
        // stage x tile transposed via 4x4 micro-tile per thread
        {
            int r0 = rh * 4, q0 = qh * 4;
            float4 v0 = {0,0,0,0}, v1 = {0,0,0,0}, v2 = {0,0,0,0}, v3 = {0,0,0,0};
            const float* xb = &x[(size_t)(row0 + r0) * FIN + kc + q0];
            if (row0 + r0 + 3 < N) {
                v0 = *(const float4*)(xb + 0 * FIN);
                v1 = *(const float4*)(xb + 1 * FIN);
                v2 = *(const float4*)(xb + 2 * FIN);
                v3 = *(const float4*)(xb + 3 * FIN);
            } else {
                if (row0 + r0 + 0 < N) v0 = *(const float4*)(xb + 0 * FIN);
                if (row0 + r0 + 1 < N) v1 = *(const float4*)(xb + 1 * FIN);
                if (row0 + r0 + 2 < N) v2 = *(const float4*)(xb + 2 * FIN);
                if (row0 + r0 + 3 < N) v3 = *(const float4*)(xb + 3 * FIN);
            }
            float4 w0 = {v0.x, v1.x, v2.x, v3.x};
            float4 w1 = {v0.y, v1.y, v2.y, v3.y};
            float4 w2 = {v0.z, v1.z, v2.z, v3.z};
            float4 w3 = {v0.w, v1.w, v2.w, v3.w};
            *(float4*)&xs_t[(q0 + 0) * G1_XP + r0] = w0;
            *(float4*)&xs_t[(q0 + 1) * G1_XP + r0] = w1;
            *(float4*)&xs_t[(q0 + 2) * G1_XP + r0] = w2;
            *(float4*)&xs_t[(q0 + 3) * G1_XP + r0] = w3;
        }
        __syncthreads();
        #pragma unroll 2
        for (int k = 0; k < G1_KC; k++) {
            const float* wp = &wsh[k * G1_WP + tc * 8];
            float4 wa = *(const float4*)wp;
            float4 wb = *(const float4*)(wp + 4);
            const float* xp = &xs_t[k * G1_XP + tr * 8];
            float4 xa = *(const float4*)xp;
            float4 xb4 = *(const float4*)(xp + 4);
            float xv[8] = {xa.x, xa.y, xa.z, xa.w, xb4.x, xb4.y, xb4.z, xb4.w};
            float wv[8] = {wa.x, wa.y, wa.z, wa.w, wb.x, wb.y, wb.z, wb.w};
            #pragma unroll
            for (int i = 0; i < 8; i++)
                #pragma unroll
                for (int j = 0; j < 8; j++)
                    acc[i][j] += xv[i] * wv[j];
        }
        __syncthreads();
    }
    // store 8 rows x 8 cols as bf16 (16B per row-chunk)
    #pragma unroll
    for (int i = 0; i < 8; i++) {
        int gr = row0 + tr * 8 + i;
        if (gr < N) {
            uint4 o;
            o.x = (uint)f2bf(acc[i][0]) | ((uint)f2bf(acc[i][1]) << 16);
            o.y = (uint)f2bf(acc[i][2]) | ((uint)f2bf(acc[i][3]) << 16);
            o.z = (uint)f2bf(acc[i][4]) | ((uint)f2bf(acc[i][5]) << 16);
            o.w = (uint)f2bf(acc[i][6]) | ((uint)f2bf(acc[i][7]) << 16);
            *(uint4*)&h1[(size_t)gr * FH + tc * 8] = o;
        }
    }
}

// AGG1: h[node][f] = relu(b1[f] + sum_e h1[src_e][f]*norm_e), h1 in bf16.
// 32 threads per node, 4 bf16 (8B) per thread per edge.
__global__ __launch_bounds__(256) void GCN_agg1_k(const ushort* __restrict__ h1,
                                                  const int* __restrict__ row_start,
                                                  const int* __restrict__ ssrc,
                                                  const float* __restrict__ snorm,
                                                  const float* __restrict__ b1,
                                                  float* __restrict__ h, int N) {
    int gid = blockIdx.x * 256 + threadIdx.x;
    int node = gid >> 5;
    if (node >= N) return;
    int j = gid & 31;                 // cols j*4 .. j*4+3
    int beg = row_start[node], end = row_start[node + 1];
    float a0 = 0.f, a1 = 0.f, a2 = 0.f, a3 = 0.f;
    for (int i = beg; i < end; i++) {
        int s = ssrc[i];
        float w = snorm[i];
        uint2 raw = *(const uint2*)&h1[(size_t)s * FH + j * 4];
        float f0 = __uint_as_float(raw.x << 16);
        float f1 = __uint_as_float(raw.x & 0xFFFF0000u);
        float f2 = __uint_as_float(raw.y << 16);
        float f3 = __uint_as_float(raw.y & 0xFFFF0000u);
        a0 += f0 * w; a1 += f1 * w; a2 += f2 * w; a3 += f3 * w;
    }
    float4 bb = ((const float4*)b1)[j];
    float4 o;
    o.x = fmaxf(a0 + bb.x, 0.f);
    o.y = fmaxf(a1 + bb.y, 0.f);
    o.z = fmaxf(a2 + bb.z, 0.f);
    o.w = fmaxf(a3 + bb.w, 0.f);
    ((float4*)h)[(size_t)node * (FH / 4) + j] = o;
}

// GEMM2: h2[N][16] = h[N][128] @ W2[128][16].
__global__ __launch_bounds__(256) void GCN_gemm2_k(const float* __restrict__ h,
                                                   const float* __restrict__ W2,
                                                   float* __restrict__ h2, int N) {
    __shared__ float w2s[FH][FO];
    __shared__ float hs[16][FH + 4];
    int tid = threadIdx.x;
    #pragma unroll
    for (int j = 0; j < (FH * FO) / 256; j++) {
        int i = tid + j * 256;
        w2s[i >> 4][i & 15] = W2[i];
    }
    int row0 = blockIdx.x * 16;
    #pragma unroll
    for (int j = 0; j < (16 * FH) / 256; j++) {
        int i = tid + j * 256;
        int r = i >> 7, k = i & 127;
        int gr = row0 + r;
        hs[r][k] = (gr < N) ? h[gr * FH + k] : 0.f;
    }
    __syncthreads();
    int r = tid >> 4, f = tid & 15;
    float acc = 0.f;
    for (int k = 0; k < FH; k++) acc += hs[r][k] * w2s[k][f];
    int gr = row0 + r;
    if (gr < N) h2[gr * FO + f] = acc;
}

// AGG2 + bias + log_softmax fused.
__global__ __launch_bounds__(256) void GCN_agg2_k(const float* __restrict__ h2,
                                                  const int* __restrict__ row_start,
                                                  const int* __restrict__ ssrc,
                                                  const float* __restrict__ snorm,
                                                  const float* __restrict__ b2,
                                                  float* __restrict__ out, int N) {
    int tid = threadIdx.x;
    int node = blockIdx.x * 16 + (tid >> 4);
    if (node >= N) return;
    int f = tid & 15;
    int beg = row_start[node], end = row_start[node + 1];
    float acc = 0.f;
    for (int i = beg; i < end; i++) {
        acc += h2[ssrc[i] * FO + f] * snorm[i];
    }
    float v = acc + b2[f];
    float mx = v;
    #pragma unroll
    for (int m = 8; m >= 1; m >>= 1) mx = fmaxf(mx, __shfl_xor(mx, m, 16));
    float e = expf(v - mx);
    float sum = e;
    #pragma unroll
    for (int m = 8; m >= 1; m >>= 1) sum += __shfl_xor(sum, m, 16);
    out[node * FO + f] = v - mx - logf(sum);
}

extern "C" void kernel_launch(void* const* d_in, const int* in_sizes, int n_in,
                              void* d_out, int out_size, void* d_ws, size_t ws_size,
                              hipStream_t stream) {
    (void)n_in; (void)out_size; (void)ws_size;
    const float* x  = (const float*)d_in[0];
    const int*   ed = (const int*)d_in[1];
    const float* W1 = (const float*)d_in[2];
    const float* b1 = (const float*)d_in[3];
    const float* W2 = (const float*)d_in[4];
    const float* b2 = (const float*)d_in[5];
    float* out = (float*)d_out;

    int N = in_sizes[0] / FIN;   // 50000
    int E = in_sizes[1] / 2;     // 800000
    int M = E + N;
    int nScanBlocks = (N + SCAN_CHUNK - 1) / SCAN_CHUNK;

    char* p = (char*)d_ws;
    auto take = [&](size_t bytes) -> char* {
        char* r = p;
        p += (bytes + 255) & ~(size_t)255;
        return r;
    };
    int*    count  = (int*)take((size_t)N * 4);
    int*    cursor = (int*)take((size_t)N * 4);
    int*    rs     = (int*)take((size_t)(N + 1) * 4);
    float*  dinv   = (float*)take((size_t)N * 4);
    int*    bsum   = (int*)take((size_t)nScanBlocks * 4);
    int*    ssrc   = (int*)take((size_t)M * 4);
    float*  snorm  = (float*)take((size_t)M * 4);
    ushort* h1     = (ushort*)take((size_t)N * FH * 2);
    float*  h      = (float*)take((size_t)N * FH * 4);
    float*  h2     = (float*)take((size_t)N * FO * 4);

    GCN_zero_k<<<(N + 255) / 256, 256, 0, stream>>>(count, cursor, N);
    GCN_hist_k<<<(E + 255) / 256, 256, 0, stream>>>(ed, count, E);
    GCN_bsum_k<<<nScanBlocks, 256, 0, stream>>>(count, bsum, N);
    GCN_scan2_k<<<nScanBlocks, 256, 0, stream>>>(count, bsum, rs, dinv, N);
    GCN_fill_k<<<(M + 255) / 256, 256, 0, stream>>>(ed, rs, cursor, dinv, ssrc, snorm, E, N);
    GCN_gemm1_k<<<(N + G1_BR - 1) / G1_BR, 256, 0, stream>>>(x, W1, h1, N);
    GCN_agg1_k<<<((size_t)N * 32 + 255) / 256, 256, 0, stream>>>(h1, rs, ssrc, snorm, b1, h, N);
    GCN_gemm2_k<<<(N + 15) / 16, 256, 0, stream>>>(h, W2, h2, N);
    GCN_agg2_k<<<(N + 15) / 16, 256, 0, stream>>>(h2, rs, ssrc, snorm, b2, out, N);
}

// Round 5
// 220.562 us; speedup vs baseline: 1.6901x; 1.1322x over previous
//
#include <hip/hip_runtime.h>
#include <hip/hip_bf16.h>
#include <math.h>

// ---------------------------------------------------------------------------
// GCN 2-layer forward. Pipeline:
//   1) zero counters
//   2) histogram of dst (in-degree)
//   3) parallel scan: bsum_k + scan2_k -> row_start, dinv
//   4) counting-sort fill: CSR (sorted_src, sorted_norm) grouped by dst
//   4b) wprep: W1^T -> bf16 hi/lo split (whT, wlT), once
//   5) GEMM1 (MFMA): h1(bf16) = x @ W1 via 3-pass split bf16
//        xh*wh + xl*wh + xh*wl, fp32 accum -> ~fp32-exact
//   6) AGG1:  h(f32) = relu(gather-sum(h1[src]*norm) + b1)  [bf16 gather]
//   7) GEMM2: h2 = h @ W2
//   8) AGG2 + bias + log_softmax fused
// ---------------------------------------------------------------------------

#define FIN 256
#define FH  128
#define FO  16
#define SCAN_CHUNK 1024

typedef unsigned int uint;
typedef unsigned short ushort;
typedef __attribute__((ext_vector_type(8))) short bf16x8;
typedef __attribute__((ext_vector_type(4))) float f32x4;

static __device__ __forceinline__ ushort f2bf(float f) {
    __hip_bfloat16 b = __float2bfloat16(f);
    return *reinterpret_cast<ushort*>(&b);
}
static __device__ __forceinline__ float bf2f(ushort u) {
    return __uint_as_float(((uint)u) << 16);
}

__global__ __launch_bounds__(256) void GCN_zero_k(int* __restrict__ count,
                                                  int* __restrict__ cursor, int N) {
    int i = blockIdx.x * 256 + threadIdx.x;
    if (i < N) { count[i] = 0; cursor[i] = 0; }
}

__global__ __launch_bounds__(256) void GCN_hist_k(const int* __restrict__ edge,
                                                  int* __restrict__ count, int E) {
    int i = blockIdx.x * 256 + threadIdx.x;
    if (i < E) atomicAdd(&count[edge[E + i]], 1);
}

__global__ __launch_bounds__(256) void GCN_bsum_k(const int* __restrict__ count,
                                                  int* __restrict__ bsum, int N) {
    int tid = threadIdx.x;
    int i0 = blockIdx.x * SCAN_CHUNK + tid * 4;
    int s = 0;
    if (i0 + 3 < N) {
        int4 c = *(const int4*)&count[i0];
        s = c.x + c.y + c.z + c.w + 4;
    } else {
        for (int j = 0; j < 4; j++)
            if (i0 + j < N) s += count[i0 + j] + 1;
    }
    __shared__ int red[256];
    red[tid] = s;
    __syncthreads();
    for (int st = 128; st > 0; st >>= 1) {
        if (tid < st) red[tid] += red[tid + st];
        __syncthreads();
    }
    if (tid == 0) bsum[blockIdx.x] = red[0];
}

__global__ __launch_bounds__(256) void GCN_scan2_k(const int* __restrict__ count,
                                                   const int* __restrict__ bsum,
                                                   int* __restrict__ row_start,
                                                   float* __restrict__ dinv, int N) {
    int tid = threadIdx.x;
    int b = blockIdx.x;
    int i0 = b * SCAN_CHUNK + tid * 4;

    int v0 = 0, v1 = 0, v2 = 0, v3 = 0;
    if (i0 + 3 < N) {
        int4 c = *(const int4*)&count[i0];
        v0 = c.x + 1; v1 = c.y + 1; v2 = c.z + 1; v3 = c.w + 1;
    } else {
        if (i0 + 0 < N) v0 = count[i0 + 0] + 1;
        if (i0 + 1 < N) v1 = count[i0 + 1] + 1;
        if (i0 + 2 < N) v2 = count[i0 + 2] + 1;
        if (i0 + 3 < N) v3 = count[i0 + 3] + 1;
    }
    int lsum = v0 + v1 + v2 + v3;

    __shared__ int red[256];
    int offp = 0;
    for (int t = tid; t < b; t += 256) offp += bsum[t];
    red[tid] = offp;
    __syncthreads();
    for (int st = 128; st > 0; st >>= 1) {
        if (tid < st) red[tid] += red[tid + st];
        __syncthreads();
    }
    int blockOff = red[0];
    __syncthreads();

    __shared__ int ssum[256];
    ssum[tid] = lsum;
    __syncthreads();
    for (int off = 1; off < 256; off <<= 1) {
        int t = (tid >= off) ? ssum[tid - off] : 0;
        __syncthreads();
        ssum[tid] += t;
        __syncthreads();
    }
    int r = blockOff + (tid == 0 ? 0 : ssum[tid - 1]);

    if (i0 + 0 < N) { row_start[i0 + 0] = r; dinv[i0 + 0] = rsqrtf((float)v0); r += v0; }
    if (i0 + 1 < N) { row_start[i0 + 1] = r; dinv[i0 + 1] = rsqrtf((float)v1); r += v1; }
    if (i0 + 2 < N) { row_start[i0 + 2] = r; dinv[i0 + 2] = rsqrtf((float)v2); r += v2; }
    if (i0 + 3 < N) { row_start[i0 + 3] = r; dinv[i0 + 3] = rsqrtf((float)v3); r += v3; }

    if (b == gridDim.x - 1 && tid == 255) row_start[N] = blockOff + ssum[255];
}

__global__ __launch_bounds__(256) void GCN_fill_k(const int* __restrict__ edge,
                                                  const int* __restrict__ row_start,
                                                  int* __restrict__ cursor,
                                                  const float* __restrict__ dinv,
                                                  int* __restrict__ ssrc,
                                                  float* __restrict__ snorm,
                                                  int E, int N) {
    int i = blockIdx.x * 256 + threadIdx.x;
    if (i < E) {
        int s = edge[i];
        int d = edge[E + i];
        int p = atomicAdd(&cursor[d], 1);
        int idx = row_start[d] + p;
        ssrc[idx] = s;
        snorm[idx] = dinv[s] * dinv[d];
    } else if (i < E + N) {
        int v = i - E;
        int p = atomicAdd(&cursor[v], 1);
        int idx = row_start[v] + p;
        ssrc[idx] = v;
        float q = dinv[v];
        snorm[idx] = q * q;
    }
}

// W-prep: W1[256][128] fp32 -> whT/wlT [128 cols][256 k] bf16 hi/lo split.
__global__ __launch_bounds__(256) void GCN_wprep_k(const float* __restrict__ W1,
                                                   ushort* __restrict__ whT,
                                                   ushort* __restrict__ wlT) {
    int i = blockIdx.x * 256 + threadIdx.x;   // 32768
    int k = i >> 7, c = i & 127;
    float w = W1[i];
    ushort hh = f2bf(w);
    ushort hl = f2bf(w - bf2f(hh));
    whT[c * 256 + k] = hh;
    wlT[c * 256 + k] = hl;
}

// GEMM1 (MFMA): h1(bf16)[N][128] = x[N][256] @ W1[256][128]
// 256 thr = 4 waves. Tile M=64, N=128 (full), K chunks of 64.
// Wave w covers cols [w*32, w*32+32): 4 row-subtiles x 2 col-subtiles of 16x16.
// LDS tiles [outer][64k] bf16, XOR swizzle byte^=((row&7)<<4) -> conflict-free
// ds_read_b128 fragments. 3-pass split precision (xh*wh + xl*wh + xh*wl).
#define G1_BR 64
#define G1_KC 64
__global__ __launch_bounds__(256, 2) void GCN_gemm1_k(const float* __restrict__ x,
                                                      const ushort* __restrict__ whT,
                                                      const ushort* __restrict__ wlT,
                                                      ushort* __restrict__ h1,
                                                      int N) {
    __shared__ __align__(16) ushort xh_s[G1_BR * G1_KC];   // 8 KiB
    __shared__ __align__(16) ushort xl_s[G1_BR * G1_KC];   // 8 KiB
    __shared__ __align__(16) ushort wh_s[FH * G1_KC];      // 16 KiB
    __shared__ __align__(16) ushort wl_s[FH * G1_KC];      // 16 KiB

    int tid = threadIdx.x;
    int row0 = blockIdx.x * G1_BR;
    int ln = tid & 63;
    int w  = tid >> 6;          // wave 0..3
    int ln15 = ln & 15;
    int q16  = ln >> 4;         // 0..3
    int sw   = (ln15 & 7) << 4; // XOR swizzle constant for this lane

    f32x4 acc[4][2];
    #pragma unroll
    for (int mr = 0; mr < 4; mr++)
        #pragma unroll
        for (int nc = 0; nc < 2; nc++) acc[mr][nc] = (f32x4){0.f, 0.f, 0.f, 0.f};

    for (int kc = 0; kc < FIN; kc += G1_KC) {
        // stage x tile [64 rows][64 k]: 1024 float4 units / 256 thr = 4 each
        #pragma unroll
        for (int j = 0; j < 4; j++) {
            int uu = tid + j * 256;
            int r = uu >> 4, kq = uu & 15;       // 16 float4 per row
            int gr = row0 + r;
            float4 v = make_float4(0.f, 0.f, 0.f, 0.f);
            if (gr < N) v = *(const float4*)&x[(size_t)gr * FIN + kc + kq * 4];
            ushort h0 = f2bf(v.x), h1v = f2bf(v.y), h2 = f2bf(v.z), h3 = f2bf(v.w);
            ushort l0 = f2bf(v.x - bf2f(h0));
            ushort l1 = f2bf(v.y - bf2f(h1v));
            ushort l2 = f2bf(v.z - bf2f(h2));
            ushort l3 = f2bf(v.w - bf2f(h3));
            uint2 hw, lw;
            hw.x = (uint)h0 | ((uint)h1v << 16);
            hw.y = (uint)h2 | ((uint)h3 << 16);
            lw.x = (uint)l0 | ((uint)l1 << 16);
            lw.y = (uint)l2 | ((uint)l3 << 16);
            int byte = (r * 128 + kq * 8) ^ ((r & 7) << 4);
            *(uint2*)((char*)xh_s + byte) = hw;
            *(uint2*)((char*)xl_s + byte) = lw;
        }
        // stage W tiles [128 cols][64 k]: 1024 16B units / 256 thr = 4 each
        #pragma unroll
        for (int j = 0; j < 4; j++) {
            int uu = tid + j * 256;
            int c = uu >> 3, ku = uu & 7;        // 8 16B-units per col
            uint4 vh = *(const uint4*)&whT[(size_t)c * 256 + kc + ku * 8];
            uint4 vl = *(const uint4*)&wlT[(size_t)c * 256 + kc + ku * 8];
            int byte = (c * 128 + ku * 16) ^ ((c & 7) << 4);
            *(uint4*)((char*)wh_s + byte) = vh;
            *(uint4*)((char*)wl_s + byte) = vl;
        }
        __syncthreads();

        #pragma unroll
        for (int ks = 0; ks < 2; ks++) {
            int kk = (ks * 64 + q16 * 16) ^ sw;   // swizzled byte offset in row
            bf16x8 ah[4], al[4], bh[2], bl[2];
            #pragma unroll
            for (int mr = 0; mr < 4; mr++) {
                int r = mr * 16 + ln15;
                ah[mr] = *(const bf16x8*)((const char*)xh_s + r * 128 + kk);
                al[mr] = *(const bf16x8*)((const char*)xl_s + r * 128 + kk);
            }
            #pragma unroll
            for (int nc = 0; nc < 2; nc++) {
                int c = w * 32 + nc * 16 + ln15;
                bh[nc] = *(const bf16x8*)((const char*)wh_s + c * 128 + kk);
                bl[nc] = *(const bf16x8*)((const char*)wl_s + c * 128 + kk);
            }
            #pragma unroll
            for (int mr = 0; mr < 4; mr++)
                #pragma unroll
                for (int nc = 0; nc < 2; nc++) {
                    acc[mr][nc] = __builtin_amdgcn_mfma_f32_16x16x32_bf16(
                        ah[mr], bh[nc], acc[mr][nc], 0, 0, 0);
                    acc[mr][nc] = __builtin_amdgcn_mfma_f32_16x16x32_bf16(
                        al[mr], bh[nc], acc[mr][nc], 0, 0, 0);
                    acc[mr][nc] = __builtin_amdgcn_mfma_f32_16x16x32_bf16(
                        ah[mr], bl[nc], acc[mr][nc], 0, 0, 0);
                }
        }
        __syncthreads();
    }

    // epilogue: D layout col=lane&15, row=(lane>>4)*4+reg  [m89-verified]
    #pragma unroll
    for (int mr = 0; mr < 4; mr++) {
        #pragma unroll
        for (int nc = 0; nc < 2; nc++) {
            int cw = w * 32 + nc * 16 + ln15;
            #pragma unroll
            for (int j = 0; j < 4; j++) {
                int gr = row0 + mr * 16 + q16 * 4 + j;
                if (gr < N) h1[(size_t)gr * FH + cw] = f2bf(acc[mr][nc][j]);
            }
        }
    }
}

// AGG1: h[node][f] = relu(b1[f] + sum_e h1[src_e][f]*norm_e), h1 in bf16.
__global__ __launch_bounds__(256) void GCN_agg1_k(const ushort* __restrict__ h1,
                                                  const int* __restrict__ row_start,
                                                  const int* __restrict__ ssrc,
                                                  const float* __restrict__ snorm,
                                                  const float* __restrict__ b1,
                                                  float* __restrict__ h, int N) {
    int gid = blockIdx.x * 256 + threadIdx.x;
    int node = gid >> 5;
    if (node >= N) return;
    int j = gid & 31;                 // cols j*4 .. j*4+3
    int beg = row_start[node], end = row_start[node + 1];
    float a0 = 0.f, a1 = 0.f, a2 = 0.f, a3 = 0.f;
    for (int i = beg; i < end; i++) {
        int s = ssrc[i];
        float w = snorm[i];
        uint2 raw = *(const uint2*)&h1[(size_t)s * FH + j * 4];
        float f0 = __uint_as_float(raw.x << 16);
        float f1 = __uint_as_float(raw.x & 0xFFFF0000u);
        float f2 = __uint_as_float(raw.y << 16);
        float f3 = __uint_as_float(raw.y & 0xFFFF0000u);
        a0 += f0 * w; a1 += f1 * w; a2 += f2 * w; a3 += f3 * w;
    }
    float4 bb = ((const float4*)b1)[j];
    float4 o;
    o.x = fmaxf(a0 + bb.x, 0.f);
    o.y = fmaxf(a1 + bb.y, 0.f);
    o.z = fmaxf(a2 + bb.z, 0.f);
    o.w = fmaxf(a3 + bb.w, 0.f);
    ((float4*)h)[(size_t)node * (FH / 4) + j] = o;
}

// GEMM2: h2[N][16] = h[N][128] @ W2[128][16].
__global__ __launch_bounds__(256) void GCN_gemm2_k(const float* __restrict__ h,
                                                   const float* __restrict__ W2,
                                                   float* __restrict__ h2, int N) {
    __shared__ float w2s[FH][FO];
    __shared__ float hs[16][FH + 4];
    int tid = threadIdx.x;
    #pragma unroll
    for (int j = 0; j < (FH * FO) / 256; j++) {
        int i = tid + j * 256;
        w2s[i >> 4][i & 15] = W2[i];
    }
    int row0 = blockIdx.x * 16;
    #pragma unroll
    for (int j = 0; j < (16 * FH) / 256; j++) {
        int i = tid + j * 256;
        int r = i >> 7, k = i & 127;
        int gr = row0 + r;
        hs[r][k] = (gr < N) ? h[gr * FH + k] : 0.f;
    }
    __syncthreads();
    int r = tid >> 4, f = tid & 15;
    float acc = 0.f;
    for (int k = 0; k < FH; k++) acc += hs[r][k] * w2s[k][f];
    int gr = row0 + r;
    if (gr < N) h2[gr * FO + f] = acc;
}

// AGG2 + bias + log_softmax fused.
__global__ __launch_bounds__(256) void GCN_agg2_k(const float* __restrict__ h2,
                                                  const int* __restrict__ row_start,
                                                  const int* __restrict__ ssrc,
                                                  const float* __restrict__ snorm,
                                                  const float* __restrict__ b2,
                                                  float* __restrict__ out, int N) {
    int tid = threadIdx.x;
    int node = blockIdx.x * 16 + (tid >> 4);
    if (node >= N) return;
    int f = tid & 15;
    int beg = row_start[node], end = row_start[node + 1];
    float acc = 0.f;
    for (int i = beg; i < end; i++) {
        acc += h2[ssrc[i] * FO + f] * snorm[i];
    }
    float v = acc + b2[f];
    float mx = v;
    #pragma unroll
    for (int m = 8; m >= 1; m >>= 1) mx = fmaxf(mx, __shfl_xor(mx, m, 16));
    float e = expf(v - mx);
    float sum = e;
    #pragma unroll
    for (int m = 8; m >= 1; m >>= 1) sum += __shfl_xor(sum, m, 16);
    out[node * FO + f] = v - mx - logf(sum);
}

extern "C" void kernel_launch(void* const* d_in, const int* in_sizes, int n_in,
                              void* d_out, int out_size, void* d_ws, size_t ws_size,
                              hipStream_t stream) {
    (void)n_in; (void)out_size; (void)ws_size;
    const float* x  = (const float*)d_in[0];
    const int*   ed = (const int*)d_in[1];
    const float* W1 = (const float*)d_in[2];
    const float* b1 = (const float*)d_in[3];
    const float* W2 = (const float*)d_in[4];
    const float* b2 = (const float*)d_in[5];
    float* out = (float*)d_out;

    int N = in_sizes[0] / FIN;   // 50000
    int E = in_sizes[1] / 2;     // 800000
    int M = E + N;
    int nScanBlocks = (N + SCAN_CHUNK - 1) / SCAN_CHUNK;

    char* p = (char*)d_ws;
    auto take = [&](size_t bytes) -> char* {
        char* r = p;
        p += (bytes + 255) & ~(size_t)255;
        return r;
    };
    int*    count  = (int*)take((size_t)N * 4);
    int*    cursor = (int*)take((size_t)N * 4);
    int*    rs     = (int*)take((size_t)(N + 1) * 4);
    float*  dinv   = (float*)take((size_t)N * 4);
    int*    bsum   = (int*)take((size_t)nScanBlocks * 4);
    int*    ssrc   = (int*)take((size_t)M * 4);
    float*  snorm  = (float*)take((size_t)M * 4);
    ushort* whT    = (ushort*)take((size_t)FH * FIN * 2);
    ushort* wlT    = (ushort*)take((size_t)FH * FIN * 2);
    ushort* h1     = (ushort*)take((size_t)N * FH * 2);
    float*  h      = (float*)take((size_t)N * FH * 4);
    float*  h2     = (float*)take((size_t)N * FO * 4);

    GCN_zero_k<<<(N + 255) / 256, 256, 0, stream>>>(count, cursor, N);
    GCN_hist_k<<<(E + 255) / 256, 256, 0, stream>>>(ed, count, E);
    GCN_bsum_k<<<nScanBlocks, 256, 0, stream>>>(count, bsum, N);
    GCN_scan2_k<<<nScanBlocks, 256, 0, stream>>>(count, bsum, rs, dinv, N);
    GCN_fill_k<<<(M + 255) / 256, 256, 0, stream>>>(ed, rs, cursor, dinv, ssrc, snorm, E, N);
    GCN_wprep_k<<<(FIN * FH) / 256, 256, 0, stream>>>(W1, whT, wlT);
    GCN_gemm1_k<<<(N + G1_BR - 1) / G1_BR, 256, 0, stream>>>(x, whT, wlT, h1, N);
    GCN_agg1_k<<<((size_t)N * 32 + 255) / 256, 256, 0, stream>>>(h1, rs, ssrc, snorm, b1, h, N);
    GCN_gemm2_k<<<(N + 15) / 16, 256, 0, stream>>>(h, W2, h2, N);
    GCN_agg2_k<<<(N + 15) / 16, 256, 0, stream>>>(h2, rs, ssrc, snorm, b2, out, N);
}

// Round 6
// 186.566 us; speedup vs baseline: 1.9981x; 1.1822x over previous
//
#include <hip/hip_runtime.h>
#include <hip/hip_bf16.h>
#include <math.h>

// ---------------------------------------------------------------------------
// GCN 2-layer forward. Pipeline:
//   1) zero counters
//   2) histogram of dst (in-degree)
//   3) parallel scan: bsum_k + scan2_k -> row_start, dinv
//   4) counting-sort fill: CSR (sorted_src, sorted_norm) grouped by dst
//   4b) wprep: W1^T -> bf16 hi/lo split (whT, wlT), once
//   5) GEMM1 (MFMA): h1(bf16) = x @ W1 via 3-pass split bf16 (fp32-exact-ish)
//   6) AGG1:  h(f32) = relu(gather-sum(h1[src]*norm) + b1)
//             16 lanes/node, edge-unroll x4 for MLP
//   7) GEMM2: h2 = h @ W2
//   8) AGG2 + bias + log_softmax fused (edge-unroll x4)
// ---------------------------------------------------------------------------

#define FIN 256
#define FH  128
#define FO  16
#define SCAN_CHUNK 1024

typedef unsigned int uint;
typedef unsigned short ushort;
typedef __attribute__((ext_vector_type(8))) short bf16x8;
typedef __attribute__((ext_vector_type(4))) float f32x4;

static __device__ __forceinline__ ushort f2bf(float f) {
    __hip_bfloat16 b = __float2bfloat16(f);
    return *reinterpret_cast<ushort*>(&b);
}
static __device__ __forceinline__ float bf2f(ushort u) {
    return __uint_as_float(((uint)u) << 16);
}

__global__ __launch_bounds__(256) void GCN_zero_k(int* __restrict__ count,
                                                  int* __restrict__ cursor, int N) {
    int i = blockIdx.x * 256 + threadIdx.x;
    if (i < N) { count[i] = 0; cursor[i] = 0; }
}

__global__ __launch_bounds__(256) void GCN_hist_k(const int* __restrict__ edge,
                                                  int* __restrict__ count, int E) {
    int i = blockIdx.x * 256 + threadIdx.x;
    if (i < E) atomicAdd(&count[edge[E + i]], 1);
}

__global__ __launch_bounds__(256) void GCN_bsum_k(const int* __restrict__ count,
                                                  int* __restrict__ bsum, int N) {
    int tid = threadIdx.x;
    int i0 = blockIdx.x * SCAN_CHUNK + tid * 4;
    int s = 0;
    if (i0 + 3 < N) {
        int4 c = *(const int4*)&count[i0];
        s = c.x + c.y + c.z + c.w + 4;
    } else {
        for (int j = 0; j < 4; j++)
            if (i0 + j < N) s += count[i0 + j] + 1;
    }
    __shared__ int red[256];
    red[tid] = s;
    __syncthreads();
    for (int st = 128; st > 0; st >>= 1) {
        if (tid < st) red[tid] += red[tid + st];
        __syncthreads();
    }
    if (tid == 0) bsum[blockIdx.x] = red[0];
}

__global__ __launch_bounds__(256) void GCN_scan2_k(const int* __restrict__ count,
                                                   const int* __restrict__ bsum,
                                                   int* __restrict__ row_start,
                                                   float* __restrict__ dinv, int N) {
    int tid = threadIdx.x;
    int b = blockIdx.x;
    int i0 = b * SCAN_CHUNK + tid * 4;

    int v0 = 0, v1 = 0, v2 = 0, v3 = 0;
    if (i0 + 3 < N) {
        int4 c = *(const int4*)&count[i0];
        v0 = c.x + 1; v1 = c.y + 1; v2 = c.z + 1; v3 = c.w + 1;
    } else {
        if (i0 + 0 < N) v0 = count[i0 + 0] + 1;
        if (i0 + 1 < N) v1 = count[i0 + 1] + 1;
        if (i0 + 2 < N) v2 = count[i0 + 2] + 1;
        if (i0 + 3 < N) v3 = count[i0 + 3] + 1;
    }
    int lsum = v0 + v1 + v2 + v3;

    __shared__ int red[256];
    int offp = 0;
    for (int t = tid; t < b; t += 256) offp += bsum[t];
    red[tid] = offp;
    __syncthreads();
    for (int st = 128; st > 0; st >>= 1) {
        if (tid < st) red[tid] += red[tid + st];
        __syncthreads();
    }
    int blockOff = red[0];
    __syncthreads();

    __shared__ int ssum[256];
    ssum[tid] = lsum;
    __syncthreads();
    for (int off = 1; off < 256; off <<= 1) {
        int t = (tid >= off) ? ssum[tid - off] : 0;
        __syncthreads();
        ssum[tid] += t;
        __syncthreads();
    }
    int r = blockOff + (tid == 0 ? 0 : ssum[tid - 1]);

    if (i0 + 0 < N) { row_start[i0 + 0] = r; dinv[i0 + 0] = rsqrtf((float)v0); r += v0; }
    if (i0 + 1 < N) { row_start[i0 + 1] = r; dinv[i0 + 1] = rsqrtf((float)v1); r += v1; }
    if (i0 + 2 < N) { row_start[i0 + 2] = r; dinv[i0 + 2] = rsqrtf((float)v2); r += v2; }
    if (i0 + 3 < N) { row_start[i0 + 3] = r; dinv[i0 + 3] = rsqrtf((float)v3); r += v3; }

    if (b == gridDim.x - 1 && tid == 255) row_start[N] = blockOff + ssum[255];
}

__global__ __launch_bounds__(256) void GCN_fill_k(const int* __restrict__ edge,
                                                  const int* __restrict__ row_start,
                                                  int* __restrict__ cursor,
                                                  const float* __restrict__ dinv,
                                                  int* __restrict__ ssrc,
                                                  float* __restrict__ snorm,
                                                  int E, int N) {
    int i = blockIdx.x * 256 + threadIdx.x;
    if (i < E) {
        int s = edge[i];
        int d = edge[E + i];
        int p = atomicAdd(&cursor[d], 1);
        int idx = row_start[d] + p;
        ssrc[idx] = s;
        snorm[idx] = dinv[s] * dinv[d];
    } else if (i < E + N) {
        int v = i - E;
        int p = atomicAdd(&cursor[v], 1);
        int idx = row_start[v] + p;
        ssrc[idx] = v;
        float q = dinv[v];
        snorm[idx] = q * q;
    }
}

// W-prep: W1[256][128] fp32 -> whT/wlT [128 cols][256 k] bf16 hi/lo split.
__global__ __launch_bounds__(256) void GCN_wprep_k(const float* __restrict__ W1,
                                                   ushort* __restrict__ whT,
                                                   ushort* __restrict__ wlT) {
    int i = blockIdx.x * 256 + threadIdx.x;   // 32768
    int k = i >> 7, c = i & 127;
    float w = W1[i];
    ushort hh = f2bf(w);
    ushort hl = f2bf(w - bf2f(hh));
    whT[c * 256 + k] = hh;
    wlT[c * 256 + k] = hl;
}

// GEMM1 (MFMA): h1(bf16)[N][128] = x[N][256] @ W1[256][128]
#define G1_BR 64
#define G1_KC 64
__global__ __launch_bounds__(256, 2) void GCN_gemm1_k(const float* __restrict__ x,
                                                      const ushort* __restrict__ whT,
                                                      const ushort* __restrict__ wlT,
                                                      ushort* __restrict__ h1,
                                                      int N) {
    __shared__ __align__(16) ushort xh_s[G1_BR * G1_KC];   // 8 KiB
    __shared__ __align__(16) ushort xl_s[G1_BR * G1_KC];   // 8 KiB
    __shared__ __align__(16) ushort wh_s[FH * G1_KC];      // 16 KiB
    __shared__ __align__(16) ushort wl_s[FH * G1_KC];      // 16 KiB

    int tid = threadIdx.x;
    int row0 = blockIdx.x * G1_BR;
    int ln = tid & 63;
    int w  = tid >> 6;          // wave 0..3
    int ln15 = ln & 15;
    int q16  = ln >> 4;         // 0..3
    int sw   = (ln15 & 7) << 4; // XOR swizzle constant for this lane

    f32x4 acc[4][2];
    #pragma unroll
    for (int mr = 0; mr < 4; mr++)
        #pragma unroll
        for (int nc = 0; nc < 2; nc++) acc[mr][nc] = (f32x4){0.f, 0.f, 0.f, 0.f};

    for (int kc = 0; kc < FIN; kc += G1_KC) {
        #pragma unroll
        for (int j = 0; j < 4; j++) {
            int uu = tid + j * 256;
            int r = uu >> 4, kq = uu & 15;
            int gr = row0 + r;
            float4 v = make_float4(0.f, 0.f, 0.f, 0.f);
            if (gr < N) v = *(const float4*)&x[(size_t)gr * FIN + kc + kq * 4];
            ushort h0 = f2bf(v.x), h1v = f2bf(v.y), h2 = f2bf(v.z), h3 = f2bf(v.w);
            ushort l0 = f2bf(v.x - bf2f(h0));
            ushort l1 = f2bf(v.y - bf2f(h1v));
            ushort l2 = f2bf(v.z - bf2f(h2));
            ushort l3 = f2bf(v.w - bf2f(h3));
            uint2 hw, lw;
            hw.x = (uint)h0 | ((uint)h1v << 16);
            hw.y = (uint)h2 | ((uint)h3 << 16);
            lw.x = (uint)l0 | ((uint)l1 << 16);
            lw.y = (uint)l2 | ((uint)l3 << 16);
            int byte = (r * 128 + kq * 8) ^ ((r & 7) << 4);
            *(uint2*)((char*)xh_s + byte) = hw;
            *(uint2*)((char*)xl_s + byte) = lw;
        }
        #pragma unroll
        for (int j = 0; j < 4; j++) {
            int uu = tid + j * 256;
            int c = uu >> 3, ku = uu & 7;
            uint4 vh = *(const uint4*)&whT[(size_t)c * 256 + kc + ku * 8];
            uint4 vl = *(const uint4*)&wlT[(size_t)c * 256 + kc + ku * 8];
            int byte = (c * 128 + ku * 16) ^ ((c & 7) << 4);
            *(uint4*)((char*)wh_s + byte) = vh;
            *(uint4*)((char*)wl_s + byte) = vl;
        }
        __syncthreads();

        #pragma unroll
        for (int ks = 0; ks < 2; ks++) {
            int kk = (ks * 64 + q16 * 16) ^ sw;
            bf16x8 ah[4], al[4], bh[2], bl[2];
            #pragma unroll
            for (int mr = 0; mr < 4; mr++) {
                int r = mr * 16 + ln15;
                ah[mr] = *(const bf16x8*)((const char*)xh_s + r * 128 + kk);
                al[mr] = *(const bf16x8*)((const char*)xl_s + r * 128 + kk);
            }
            #pragma unroll
            for (int nc = 0; nc < 2; nc++) {
                int c = w * 32 + nc * 16 + ln15;
                bh[nc] = *(const bf16x8*)((const char*)wh_s + c * 128 + kk);
                bl[nc] = *(const bf16x8*)((const char*)wl_s + c * 128 + kk);
            }
            #pragma unroll
            for (int mr = 0; mr < 4; mr++)
                #pragma unroll
                for (int nc = 0; nc < 2; nc++) {
                    acc[mr][nc] = __builtin_amdgcn_mfma_f32_16x16x32_bf16(
                        ah[mr], bh[nc], acc[mr][nc], 0, 0, 0);
                    acc[mr][nc] = __builtin_amdgcn_mfma_f32_16x16x32_bf16(
                        al[mr], bh[nc], acc[mr][nc], 0, 0, 0);
                    acc[mr][nc] = __builtin_amdgcn_mfma_f32_16x16x32_bf16(
                        ah[mr], bl[nc], acc[mr][nc], 0, 0, 0);
                }
        }
        __syncthreads();
    }

    #pragma unroll
    for (int mr = 0; mr < 4; mr++) {
        #pragma unroll
        for (int nc = 0; nc < 2; nc++) {
            int cw = w * 32 + nc * 16 + ln15;
            #pragma unroll
            for (int j = 0; j < 4; j++) {
                int gr = row0 + mr * 16 + q16 * 4 + j;
                if (gr < N) h1[(size_t)gr * FH + cw] = f2bf(acc[mr][nc][j]);
            }
        }
    }
}

// AGG1: h[node][f] = relu(b1[f] + sum_e h1[src_e][f]*norm_e), h1 in bf16.
// 16 lanes/node (16B = 8 bf16 each), edge loop unrolled x4 for MLP.
__global__ __launch_bounds__(256) void GCN_agg1_k(const ushort* __restrict__ h1,
                                                  const int* __restrict__ row_start,
                                                  const int* __restrict__ ssrc,
                                                  const float* __restrict__ snorm,
                                                  const float* __restrict__ b1,
                                                  float* __restrict__ h, int N) {
    int gid = blockIdx.x * 256 + threadIdx.x;
    int node = gid >> 4;
    if (node >= N) return;
    int j = gid & 15;                 // 16B unit j: cols 8j..8j+7
    int beg = row_start[node], end = row_start[node + 1];
    const uint4* hp = (const uint4*)h1;   // row = 16 uint4 units

    float a[8];
    #pragma unroll
    for (int t = 0; t < 8; t++) a[t] = 0.f;

    int i = beg;
    for (; i + 4 <= end; i += 4) {
        int s0 = ssrc[i + 0], s1 = ssrc[i + 1], s2 = ssrc[i + 2], s3 = ssrc[i + 3];
        float w0 = snorm[i + 0], w1 = snorm[i + 1], w2 = snorm[i + 2], w3 = snorm[i + 3];
        uint4 g0 = hp[(size_t)s0 * 16 + j];
        uint4 g1 = hp[(size_t)s1 * 16 + j];
        uint4 g2 = hp[(size_t)s2 * 16 + j];
        uint4 g3 = hp[(size_t)s3 * 16 + j];
        #pragma unroll
        for (int q = 0; q < 4; q++) {
            uint u0 = (&g0.x)[q], u1 = (&g1.x)[q], u2 = (&g2.x)[q], u3 = (&g3.x)[q];
            a[q*2+0] += __uint_as_float(u0 << 16) * w0;
            a[q*2+1] += __uint_as_float(u0 & 0xFFFF0000u) * w0;
            a[q*2+0] += __uint_as_float(u1 << 16) * w1;
            a[q*2+1] += __uint_as_float(u1 & 0xFFFF0000u) * w1;
            a[q*2+0] += __uint_as_float(u2 << 16) * w2;
            a[q*2+1] += __uint_as_float(u2 & 0xFFFF0000u) * w2;
            a[q*2+0] += __uint_as_float(u3 << 16) * w3;
            a[q*2+1] += __uint_as_float(u3 & 0xFFFF0000u) * w3;
        }
    }
    for (; i < end; i++) {
        int s = ssrc[i];
        float w = snorm[i];
        uint4 g = hp[(size_t)s * 16 + j];
        #pragma unroll
        for (int q = 0; q < 4; q++) {
            uint u = (&g.x)[q];
            a[q*2+0] += __uint_as_float(u << 16) * w;
            a[q*2+1] += __uint_as_float(u & 0xFFFF0000u) * w;
        }
    }

    const float4* bp = (const float4*)b1;   // 32 float4 units; lane j uses 2j, 2j+1
    float4 bb0 = bp[j * 2 + 0];
    float4 bb1 = bp[j * 2 + 1];
    float4 o0, o1;
    o0.x = fmaxf(a[0] + bb0.x, 0.f);
    o0.y = fmaxf(a[1] + bb0.y, 0.f);
    o0.z = fmaxf(a[2] + bb0.z, 0.f);
    o0.w = fmaxf(a[3] + bb0.w, 0.f);
    o1.x = fmaxf(a[4] + bb1.x, 0.f);
    o1.y = fmaxf(a[5] + bb1.y, 0.f);
    o1.z = fmaxf(a[6] + bb1.z, 0.f);
    o1.w = fmaxf(a[7] + bb1.w, 0.f);
    float4* op = (float4*)h;
    op[(size_t)node * 32 + j * 2 + 0] = o0;
    op[(size_t)node * 32 + j * 2 + 1] = o1;
}

// GEMM2: h2[N][16] = h[N][128] @ W2[128][16].
__global__ __launch_bounds__(256) void GCN_gemm2_k(const float* __restrict__ h,
                                                   const float* __restrict__ W2,
                                                   float* __restrict__ h2, int N) {
    __shared__ float w2s[FH][FO];
    __shared__ float hs[16][FH + 4];
    int tid = threadIdx.x;
    #pragma unroll
    for (int j = 0; j < (FH * FO) / 256; j++) {
        int i = tid + j * 256;
        w2s[i >> 4][i & 15] = W2[i];
    }
    int row0 = blockIdx.x * 16;
    #pragma unroll
    for (int j = 0; j < (16 * FH) / 256; j++) {
        int i = tid + j * 256;
        int r = i >> 7, k = i & 127;
        int gr = row0 + r;
        hs[r][k] = (gr < N) ? h[gr * FH + k] : 0.f;
    }
    __syncthreads();
    int r = tid >> 4, f = tid & 15;
    float acc = 0.f;
    for (int k = 0; k < FH; k++) acc += hs[r][k] * w2s[k][f];
    int gr = row0 + r;
    if (gr < N) h2[gr * FO + f] = acc;
}

// AGG2 + bias + log_softmax fused. 16 lanes/node, edge-unroll x4.
__global__ __launch_bounds__(256) void GCN_agg2_k(const float* __restrict__ h2,
                                                  const int* __restrict__ row_start,
                                                  const int* __restrict__ ssrc,
                                                  const float* __restrict__ snorm,
                                                  const float* __restrict__ b2,
                                                  float* __restrict__ out, int N) {
    int tid = threadIdx.x;
    int node = blockIdx.x * 16 + (tid >> 4);
    if (node >= N) return;
    int f = tid & 15;
    int beg = row_start[node], end = row_start[node + 1];
    float acc = 0.f;
    int i = beg;
    for (; i + 4 <= end; i += 4) {
        int s0 = ssrc[i + 0], s1 = ssrc[i + 1], s2 = ssrc[i + 2], s3 = ssrc[i + 3];
        float w0 = snorm[i + 0], w1 = snorm[i + 1], w2 = snorm[i + 2], w3 = snorm[i + 3];
        float g0 = h2[(size_t)s0 * FO + f];
        float g1 = h2[(size_t)s1 * FO + f];
        float g2 = h2[(size_t)s2 * FO + f];
        float g3 = h2[(size_t)s3 * FO + f];
        acc += g0 * w0 + g1 * w1 + g2 * w2 + g3 * w3;
    }
    for (; i < end; i++) {
        acc += h2[(size_t)ssrc[i] * FO + f] * snorm[i];
    }
    float v = acc + b2[f];
    float mx = v;
    #pragma unroll
    for (int m = 8; m >= 1; m >>= 1) mx = fmaxf(mx, __shfl_xor(mx, m, 16));
    float e = expf(v - mx);
    float sum = e;
    #pragma unroll
    for (int m = 8; m >= 1; m >>= 1) sum += __shfl_xor(sum, m, 16);
    out[node * FO + f] = v - mx - logf(sum);
}

extern "C" void kernel_launch(void* const* d_in, const int* in_sizes, int n_in,
                              void* d_out, int out_size, void* d_ws, size_t ws_size,
                              hipStream_t stream) {
    (void)n_in; (void)out_size; (void)ws_size;
    const float* x  = (const float*)d_in[0];
    const int*   ed = (const int*)d_in[1];
    const float* W1 = (const float*)d_in[2];
    const float* b1 = (const float*)d_in[3];
    const float* W2 = (const float*)d_in[4];
    const float* b2 = (const float*)d_in[5];
    float* out = (float*)d_out;

    int N = in_sizes[0] / FIN;   // 50000
    int E = in_sizes[1] / 2;     // 800000
    int M = E + N;
    int nScanBlocks = (N + SCAN_CHUNK - 1) / SCAN_CHUNK;

    char* p = (char*)d_ws;
    auto take = [&](size_t bytes) -> char* {
        char* r = p;
        p += (bytes + 255) & ~(size_t)255;
        return r;
    };
    int*    count  = (int*)take((size_t)N * 4);
    int*    cursor = (int*)take((size_t)N * 4);
    int*    rs     = (int*)take((size_t)(N + 1) * 4);
    float*  dinv   = (float*)take((size_t)N * 4);
    int*    bsum   = (int*)take((size_t)nScanBlocks * 4);
    int*    ssrc   = (int*)take((size_t)M * 4);
    float*  snorm  = (float*)take((size_t)M * 4);
    ushort* whT    = (ushort*)take((size_t)FH * FIN * 2);
    ushort* wlT    = (ushort*)take((size_t)FH * FIN * 2);
    ushort* h1     = (ushort*)take((size_t)N * FH * 2);
    float*  h      = (float*)take((size_t)N * FH * 4);
    float*  h2     = (float*)take((size_t)N * FO * 4);

    GCN_zero_k<<<(N + 255) / 256, 256, 0, stream>>>(count, cursor, N);
    GCN_hist_k<<<(E + 255) / 256, 256, 0, stream>>>(ed, count, E);
    GCN_bsum_k<<<nScanBlocks, 256, 0, stream>>>(count, bsum, N);
    GCN_scan2_k<<<nScanBlocks, 256, 0, stream>>>(count, bsum, rs, dinv, N);
    GCN_fill_k<<<(M + 255) / 256, 256, 0, stream>>>(ed, rs, cursor, dinv, ssrc, snorm, E, N);
    GCN_wprep_k<<<(FIN * FH) / 256, 256, 0, stream>>>(W1, whT, wlT);
    GCN_gemm1_k<<<(N + G1_BR - 1) / G1_BR, 256, 0, stream>>>(x, whT, wlT, h1, N);
    GCN_agg1_k<<<((size_t)N * 16 + 255) / 256, 256, 0, stream>>>(h1, rs, ssrc, snorm, b1, h, N);
    GCN_gemm2_k<<<(N + 15) / 16, 256, 0, stream>>>(h, W2, h2, N);
    GCN_agg2_k<<<(N + 15) / 16, 256, 0, stream>>>(h2, rs, ssrc, snorm, b2, out, N);
}